// Round 12
// baseline (263.576 us; speedup 1.0000x reference)
//
#include <hip/hip_runtime.h>

// Grouped_Soft_GSL_Block_PE fused kernel for MI355X (gfx950).
// B=8, IC2=128, N=2048, K=32, C=64, G=8, CPG=8, hidden=16.
// R12: 3-blocks/CU design. 1024 blocks x 16 n (4 iters of 4 n), 256 thr /
// 4 waves; wave wv owns n = nblk+4it+wv; zero barriers in loop.
// All weight A-fragments pre-packed bf16 frag-linear into d_ws by prep
// kernel (L1/L2-resident, 1KB/wave coalesced loads) -> LDS = xbuf+tabs
// only (35.6KB <= 53.3KB for 3 blocks/CU); __launch_bounds__(256,3).
// vmcnt ordering: weight loads issue BEFORE the HBM x-prefetch each iter
// (in-order retirement => weight waits never chain behind HBM loads).

typedef __attribute__((ext_vector_type(8))) short bf16x8;
typedef __attribute__((ext_vector_type(4))) float f32x4;

#define EPS_BN 1e-5f

// d_ws byte offsets
#define WSA   0        // main A-frags [m*4+ks][lane] 24*1024 = 24576
#define WSP   24576    // pos2 frags [m2*2+ks][lane] 8*1024 = 8192
#define WSPE  32768    // peW2 frags [ks][lane] 2*1024 = 2048
#define WSPW1 34816    // pos_w1 packed [m2][lane] uint2 = 2048
#define WSGAF 36864    // gate/attn-2 frag [lane] = 1024
#define WSLCR 37888    // combined logit consts [16] f32 = 64

__device__ __forceinline__ unsigned pk2(float a, float b){
  unsigned ua = __float_as_uint(a) + 0x8000u;
  unsigned ub = __float_as_uint(b) + 0x8000u;
  return __builtin_amdgcn_perm(ub, ua, 0x07060302);
}
__device__ __forceinline__ float lrelu(float v){ return fmaxf(v, 0.2f*v); }

__device__ __forceinline__ bf16x8 ld8(const short* p){
  union { bf16x8 v; uint2 q[2]; } w;
  w.q[0] = *(const uint2*)(p);
  w.q[1] = *(const uint2*)(p + 4);
  return w.v;
}

// DPP row_ror reductions over the 16-lane row (l15 = k dimension)
template<int N>
__device__ __forceinline__ float ror16(float x){
  return __int_as_float(__builtin_amdgcn_mov_dpp(__float_as_int(x), 0x120+N, 0xF, 0xF, false));
}
__device__ __forceinline__ float rsum16(float v){
  v += ror16<1>(v); v += ror16<2>(v); v += ror16<4>(v); v += ror16<8>(v); return v;
}
__device__ __forceinline__ float rmax16(float v){
  v = fmaxf(v, ror16<1>(v)); v = fmaxf(v, ror16<2>(v));
  v = fmaxf(v, ror16<4>(v)); v = fmaxf(v, ror16<8>(v)); return v;
}

#define MFMA16(a,b,c) __builtin_amdgcn_mfma_f32_16x16x32_bf16((a),(b),(c),0,0,0)

__global__ void gsl_prep(const float* __restrict__ trans_w, const float* __restrict__ gate_w1,
                         const float* __restrict__ attn_w1, const float* __restrict__ pos_w2,
                         const float* __restrict__ pe_w,    const float* __restrict__ pe_b,
                         const float* __restrict__ pos_b2,  const float* __restrict__ pos_w1,
                         const float* __restrict__ gate_w2, const float* __restrict__ attn_w2,
                         const float* __restrict__ attn_b2, char* __restrict__ ws){
  const int t = threadIdx.x;   // 512 threads
  // main A-frags: 24 frags x 64 lanes
  for (int idx = t; idx < 1536; idx += 512){
    int id = idx >> 6, lane = idx & 63;
    int m = id >> 2, ks = id & 3, l15 = lane & 15, g4 = lane >> 4;
    const float* src = (m < 4)  ? (trans_w + (16*m + l15)*128)
                     : (m == 4) ? (gate_w1 + l15*128)
                                : (attn_w1 + l15*128);
    src += 32*ks + 8*g4;
    uint4 u;
    u.x = pk2(src[0],src[1]); u.y = pk2(src[2],src[3]);
    u.z = pk2(src[4],src[5]); u.w = pk2(src[6],src[7]);
    *(uint4*)(ws + WSA + idx*16) = u;
  }
  // pos2 frags: 8 x 64
  {
    int id = t >> 6, lane = t & 63, l15 = lane & 15, g4 = lane >> 4;
    const float* src = pos_w2 + (16*(id>>1) + l15)*64 + 32*(id&1) + 8*g4;
    uint4 u;
    u.x = pk2(src[0],src[1]); u.y = pk2(src[2],src[3]);
    u.z = pk2(src[4],src[5]); u.w = pk2(src[6],src[7]);
    *(uint4*)(ws + WSP + t*16) = u;
  }
  // peW2 frags: 2 x 64 (rows >=8 zero)
  if (t < 128){
    int ks = t >> 6, lane = t & 63, l15 = lane & 15, g4 = lane >> 4;
    uint4 u = make_uint4(0u,0u,0u,0u);
    if (l15 < 8){
      float w[8];
      #pragma unroll
      for (int j = 0; j < 8; ++j){
        int c = 32*ks + 8*g4 + j;
        float s = 0.f;
        for (int k = 0; k < 64; ++k) s += pe_w[l15*64 + k] * pos_w2[k*64 + c];
        w[j] = s;
      }
      u.x = pk2(w[0],w[1]); u.y = pk2(w[2],w[3]);
      u.z = pk2(w[4],w[5]); u.w = pk2(w[6],w[7]);
    }
    *(uint4*)(ws + WSPE + t*16) = u;
  }
  // pos_w1 packed: 4 x 64 uint2 (only g4==0 lanes nonzero)
  if (t < 256){
    int m2 = t >> 6, lane = t & 63, l15 = lane & 15, g4 = lane >> 4;
    uint2 u = make_uint2(0u, 0u);
    if (g4 == 0){
      const float* rp = pos_w1 + (16*m2 + l15)*3;
      u.x = pk2(rp[0], rp[1]); u.y = pk2(rp[2], 0.f);
    }
    *(uint2*)(ws + WSPW1 + t*8) = u;
  }
  // gaf frag: rows 0..7 attn_w2 (k>=16), row 8 gate_w2 (k<16)
  if (t < 64){
    int l15 = t & 15, g4 = t >> 4;
    float v[8];
    #pragma unroll
    for (int j = 0; j < 8; ++j){
      int k = 8*g4 + j;
      float v2 = 0.f;
      if (l15 < 8)       { if (k >= 16) v2 = attn_w2[l15*16 + (k-16)]; }
      else if (l15 == 8) { if (k < 16)  v2 = gate_w2[k]; }
      v[j] = v2;
    }
    uint4 u;
    u.x = pk2(v[0],v[1]); u.y = pk2(v[2],v[3]);
    u.z = pk2(v[4],v[5]); u.w = pk2(v[6],v[7]);
    *(uint4*)(ws + WSGAF + t*16) = u;
  }
  // lcr: pe_b + attn_b2 + pe_w@pos_b2 (rows <8), else 0
  if (t < 16){
    float v = 0.f;
    if (t < 8){
      v = pe_b[t] + attn_b2[t];
      for (int c = 0; c < 64; ++c) v += pe_w[t*64 + c] * pos_b2[c];
    }
    *(float*)(ws + WSLCR + t*4) = v;
  }
}

__global__ __launch_bounds__(256, 3)
void gsl_fused(const float* __restrict__ x,      const float* __restrict__ rel_pos,
               const float* __restrict__ pos_g,  const float* __restrict__ pos_bb,
               const float* __restrict__ pos_m,  const float* __restrict__ pos_v,
               const float* __restrict__ pos_b2, const float* __restrict__ tr_g,
               const float* __restrict__ tr_bb,  const float* __restrict__ tr_m,
               const float* __restrict__ tr_v,   const float* __restrict__ ga_g,
               const float* __restrict__ ga_bb,  const float* __restrict__ ga_m,
               const float* __restrict__ ga_v,   const float* __restrict__ gate_b2,
               const float* __restrict__ at_g,   const float* __restrict__ at_bb,
               const float* __restrict__ at_m,   const float* __restrict__ at_v,
               const char* __restrict__ ws,      float* __restrict__ out)
{
  // LDS map (35584 B, 3 blocks/CU):
  // [0,33792)      xbuf [128 cols][132] bf16; wave slice 8448B at wv*8448,
  //                aliased post-GEMM per wave: h1b [32][68] @0, gab [32][36] @4352
  // [33792,35584)  tabs f32: trQ[256] (s,b,pos_b2,0 quads) p1T[128] gaT[32] atT[32]
  __shared__ __align__(16) char smem[35584];
  short* xbuf = (short*)smem;
  float* trQ  = (float*)(smem + 33792);
  float* p1T  = (float*)(smem + 34816);
  float* gaT  = (float*)(smem + 35328);
  float* atT  = (float*)(smem + 35456);

  const int tid = threadIdx.x;
  const int wv  = tid >> 6;
  const int l   = tid & 63;
  const int l15 = l & 15, g4 = l >> 4;
  const int bid = blockIdx.x;
  const int b    = bid >> 7;           // 128 blocks per batch
  const int nblk = (bid & 127) << 4;   // 16 n per block

  // ---- BN fold tables ----
  if (tid < 64){
    float s = tr_g[tid] * rsqrtf(tr_v[tid] + EPS_BN);
    *(float4*)(trQ + 4*tid) = make_float4(s, tr_bb[tid] - tr_m[tid]*s, pos_b2[tid], 0.f);
    float s2 = pos_g[tid] * rsqrtf(pos_v[tid] + EPS_BN);
    p1T[2*tid] = s2; p1T[2*tid+1] = pos_bb[tid] - pos_m[tid]*s2;
  } else if (tid < 80){
    int c = tid - 64;
    float s = ga_g[c] * rsqrtf(ga_v[c] + EPS_BN);
    gaT[2*c] = s; gaT[2*c+1] = ga_bb[c] - ga_m[c]*s;
  } else if (tid < 96){
    int c = tid - 80;
    float s = at_g[c] * rsqrtf(at_v[c] + EPS_BN);
    atT[2*c] = s; atT[2*c+1] = at_bb[c] - at_m[c]*s;
  }

  // ---- resident small frags / consts from ws (L2) ----
  uint2 pw1p[4];
  #pragma unroll
  for (int m2 = 0; m2 < 4; ++m2)
    pw1p[m2] = *(const uint2*)(ws + WSPW1 + (m2*64 + l)*8);
  bf16x8 gaf = *(const bf16x8*)(ws + WSGAF + l*16);
  float lcr[4];
  #pragma unroll
  for (int r = 0; r < 4; ++r)
    lcr[r] = *(const float*)(ws + WSLCR + (4*g4 + r)*4);
  const float gb2v = gate_b2[0];

  // ---- per-wave constants ----
  const int col0 = 32*wv + l15, col1 = col0 + 16;
  const int lc0 = l15, lc1 = l15 + 16;
  const int lq = l & 7, ld = l >> 3;
  const int colb = 32*wv + 4*lq;
  char*  slice = smem + wv*8448;
  short* h1b   = (short*)slice;            // [32][68]
  short* gab   = (short*)(slice + 4352);   // [32][36]
  const float* xp0 = x + (((long)(b*128 + 8*ld)) << 16) + colb;
  const float* rpb = rel_pos + (((long)(3*b)) << 16);
  const int och = 16*(l15 >> 2) + 4*g4 + (l15 & 3);   // butterfly output channel
  float* outb = out + (((long)(b*64 + och)) << 11) + nblk + wv;

  // ---- prologue: prefetch iteration 0 (issued LAST in preamble) ----
  f32x4 fa[8], fb[8];
  float rc[6] = {0.f,0.f,0.f,0.f,0.f,0.f};
  {
    const long sb0 = (long)nblk * 32;
    #pragma unroll
    for (int j = 0; j < 8; ++j) fa[j] = *(const f32x4*)(xp0 + sb0 + (((long)j) << 16));
    #pragma unroll
    for (int j = 0; j < 8; ++j) fb[j] = *(const f32x4*)(xp0 + sb0 + (((long)(64+j)) << 16));
    if (g4 == 0){
      long sg = sb0 + col0;
      rc[0] = rpb[sg];          rc[1] = rpb[sg + 65536];      rc[2] = rpb[sg + 131072];
      rc[3] = rpb[sg + 16];     rc[4] = rpb[sg + 65536 + 16]; rc[5] = rpb[sg + 131072 + 16];
    }
  }

  __syncthreads();   // tabs visible

  for (int it = 0; it < 4; ++it){
    const long sbase = (long)nblk*32 + 128*it;

    // (1) cvt + write staged tile -> own xbuf slice (consumes fa,fb)
    #pragma unroll
    for (int i2 = 0; i2 < 4; ++i2){
      short* dst = xbuf + (colb+i2)*132 + 8*ld;
      *(uint2*)(dst)      = make_uint2(pk2(fa[0][i2],fa[1][i2]), pk2(fa[2][i2],fa[3][i2]));
      *(uint2*)(dst + 4)  = make_uint2(pk2(fa[4][i2],fa[5][i2]), pk2(fa[6][i2],fa[7][i2]));
      *(uint2*)(dst + 64) = make_uint2(pk2(fb[0][i2],fb[1][i2]), pk2(fb[2][i2],fb[3][i2]));
      *(uint2*)(dst + 68) = make_uint2(pk2(fb[4][i2],fb[5][i2]), pk2(fb[6][i2],fb[7][i2]));
    }

    // (2) main GEMM: [96x128] @ xtile ; A-frags from ws (L1/L2-hot)
    f32x4 acc[6][2];
    #pragma unroll
    for (int m = 0; m < 6; ++m){
      f32x4 z = {0.f,0.f,0.f,0.f};
      acc[m][0] = z; acc[m][1] = z;
    }
    #pragma unroll
    for (int ks = 0; ks < 4; ++ks){
      bf16x8 b0 = ld8(xbuf + col0*132 + 32*ks + 8*g4);
      bf16x8 b1 = ld8(xbuf + col1*132 + 32*ks + 8*g4);
      #pragma unroll
      for (int m = 0; m < 6; ++m){
        bf16x8 af = *(const bf16x8*)(ws + WSA + (((m<<2)|ks)*64 + l)*16);
        acc[m][0] = MFMA16(af, b0, acc[m][0]);
        acc[m][1] = MFMA16(af, b1, acc[m][1]);
      }
    }

    // (3) pos layer 1 (K padded 3->32) -> h1b ; uses rc of CURRENT iter
    {
      bf16x8 rf0 = {0,0,0,0,0,0,0,0}, rf1 = {0,0,0,0,0,0,0,0};
      if (g4 == 0){
        union { bf16x8 v; unsigned u[4]; } t0, t1;
        t0.u[0] = pk2(rc[0], rc[1]); t0.u[1] = pk2(rc[2], 0.f); t0.u[2] = 0u; t0.u[3] = 0u;
        t1.u[0] = pk2(rc[3], rc[4]); t1.u[1] = pk2(rc[5], 0.f); t1.u[2] = 0u; t1.u[3] = 0u;
        rf0 = t0.v; rf1 = t1.v;
      }
      #pragma unroll
      for (int m2 = 0; m2 < 4; ++m2){
        union { bf16x8 v; unsigned u[4]; } aw;
        aw.u[0] = pw1p[m2].x; aw.u[1] = pw1p[m2].y; aw.u[2] = 0u; aw.u[3] = 0u;
        f32x4 z = {0.f,0.f,0.f,0.f};
        f32x4 d0 = MFMA16(aw.v, rf0, z);
        f32x4 d1 = MFMA16(aw.v, rf1, z);
        int cb2 = 16*m2 + 4*g4;
        float2 t0 = *(const float2*)(p1T + 2*(cb2+0));
        float2 t1 = *(const float2*)(p1T + 2*(cb2+1));
        float2 t2 = *(const float2*)(p1T + 2*(cb2+2));
        float2 t3 = *(const float2*)(p1T + 2*(cb2+3));
        float h0 = lrelu(t0.x*d0[0]+t0.y), h1v = lrelu(t1.x*d0[1]+t1.y);
        float h2 = lrelu(t2.x*d0[2]+t2.y), h3 = lrelu(t3.x*d0[3]+t3.y);
        *(uint2*)(h1b + lc0*68 + cb2) = make_uint2(pk2(h0,h1v), pk2(h2,h3));
        h0 = lrelu(t0.x*d1[0]+t0.y); h1v = lrelu(t1.x*d1[1]+t1.y);
        h2 = lrelu(t2.x*d1[2]+t2.y); h3 = lrelu(t3.x*d1[3]+t3.y);
        *(uint2*)(h1b + lc1*68 + cb2) = make_uint2(pk2(h0,h1v), pk2(h2,h3));
      }
    }

    // (4) trans epilogue: acc[0..3] = lrelu(BN(conv)) + pos_b2
    #pragma unroll
    for (int m = 0; m < 4; ++m)
      #pragma unroll
      for (int r = 0; r < 4; ++r){
        float4 tq = *(const float4*)(trQ + 4*(16*m + 4*g4 + r));
        acc[m][0][r] = lrelu(tq.x*acc[m][0][r] + tq.y) + tq.z;
        acc[m][1][r] = lrelu(tq.x*acc[m][1][r] + tq.y) + tq.z;
      }

    // (5) pos2 MFMAs accumulate INTO acc[0..3]; pe-fold -> pac4 (frags from ws)
    f32x4 pac4[2];
    {
      f32x4 z = {0.f,0.f,0.f,0.f};
      pac4[0] = z; pac4[1] = z;
    }
    #pragma unroll
    for (int ks = 0; ks < 2; ++ks){
      bf16x8 h0 = ld8(h1b + lc0*68 + 32*ks + 8*g4);
      bf16x8 h1v = ld8(h1b + lc1*68 + 32*ks + 8*g4);
      #pragma unroll
      for (int m2 = 0; m2 < 4; ++m2){
        bf16x8 af = *(const bf16x8*)(ws + WSP + ((m2*2 + ks)*64 + l)*16);
        acc[m2][0] = MFMA16(af, h0, acc[m2][0]);
        acc[m2][1] = MFMA16(af, h1v, acc[m2][1]);
      }
      bf16x8 af4 = *(const bf16x8*)(ws + WSPE + (ks*64 + l)*16);
      pac4[0] = MFMA16(af4, h0, pac4[0]);
      pac4[1] = MFMA16(af4, h1v, pac4[1]);
    }

    // (6) HBM prefetch for NEXT iter — issued AFTER all ws weight loads
    if (it < 3){
      const long nsb = sbase + 128;
      #pragma unroll
      for (int j = 0; j < 8; ++j) fa[j] = *(const f32x4*)(xp0 + nsb + (((long)j) << 16));
      #pragma unroll
      for (int j = 0; j < 8; ++j) fb[j] = *(const f32x4*)(xp0 + nsb + (((long)(64+j)) << 16));
      if (g4 == 0){
        long sg = nsb + col0;
        rc[0] = rpb[sg];          rc[1] = rpb[sg + 65536];      rc[2] = rpb[sg + 131072];
        rc[3] = rpb[sg + 16];     rc[4] = rpb[sg + 65536 + 16]; rc[5] = rpb[sg + 131072 + 16];
      }
    }

    // (7) hidden epilogues -> gab (gate_h ch 0..15, attn_h ch 16..31)
    {
      int hc = 4*g4;
      float2 g0p = *(const float2*)(gaT + 2*(hc+0));
      float2 g1p = *(const float2*)(gaT + 2*(hc+1));
      float2 g2p = *(const float2*)(gaT + 2*(hc+2));
      float2 g3p = *(const float2*)(gaT + 2*(hc+3));
      float2 a0p = *(const float2*)(atT + 2*(hc+0));
      float2 a1p = *(const float2*)(atT + 2*(hc+1));
      float2 a2p = *(const float2*)(atT + 2*(hc+2));
      float2 a3p = *(const float2*)(atT + 2*(hc+3));
      #pragma unroll
      for (int ct = 0; ct < 2; ++ct){
        int lc = (ct == 0) ? lc0 : lc1;
        float q0 = lrelu(g0p.x*acc[4][ct][0] + g0p.y), q1 = lrelu(g1p.x*acc[4][ct][1] + g1p.y);
        float q2 = lrelu(g2p.x*acc[4][ct][2] + g2p.y), q3 = lrelu(g3p.x*acc[4][ct][3] + g3p.y);
        *(uint2*)(gab + lc*36 + hc) = make_uint2(pk2(q0,q1), pk2(q2,q3));
        float a0 = lrelu(a0p.x*acc[5][ct][0] + a0p.y), a1 = lrelu(a1p.x*acc[5][ct][1] + a1p.y);
        float a2 = lrelu(a2p.x*acc[5][ct][2] + a2p.y), a3 = lrelu(a3p.x*acc[5][ct][3] + a3p.y);
        *(uint2*)(gab + lc*36 + 16 + hc) = make_uint2(pk2(a0,a1), pk2(a2,a3));
      }
    }

    // (8) gate/attn layer-2 MFMA (rows 0..7 attn, row 8 gate)
    f32x4 gac0 = {0.f,0.f,0.f,0.f}, gac1 = gac0;
    {
      bf16x8 g0 = ld8(gab + lc0*36 + 8*g4);
      bf16x8 g1 = ld8(gab + lc1*36 + 8*g4);
      gac0 = MFMA16(gaf, g0, gac0);
      gac1 = MFMA16(gaf, g1, gac1);
    }

    // (9) gate + logits + softmax over k (DPP reduce)
    float gv0 = __shfl(gac0[0], 32 + l15, 64);
    float gv1 = __shfl(gac1[0], 32 + l15, 64);
    float gm0 = 1.f/(1.f + __expf(-(gv0 + gb2v)));
    float gm1 = 1.f/(1.f + __expf(-(gv1 + gb2v)));
    float lg0 = __logf(gm0 + 1e-6f), lg1 = __logf(gm1 + 1e-6f);

    float wg0[4], wg1[4];
    #pragma unroll
    for (int r = 0; r < 4; ++r){
      float t0 = gac0[r] + pac4[0][r] + lcr[r] + lg0;
      float t1 = gac1[r] + pac4[1][r] + lcr[r] + lg1;
      float mx = rmax16(fmaxf(t0, t1));
      float e0 = __expf(t0 - mx), e1 = __expf(t1 - mx);
      float inv = 1.f / rsum16(e0 + e1);
      wg0[r] = e0 * inv; wg1[r] = e1 * inv;
    }

    // (10) fill vA/vM then reduce-scatter butterfly; one 64-lane store
    float vA[16], vM[16];
    const bool hi = (g4 >= 2);
    #pragma unroll
    for (int m = 0; m < 4; ++m){
      int src = 16*(m >> 1) + l15;
      float a0 = __shfl(wg0[(2*m) & 3],   src, 64);
      float b0 = __shfl(wg0[(2*m+1) & 3], src, 64);
      float a1 = __shfl(wg1[(2*m) & 3],   src, 64);
      float b1 = __shfl(wg1[(2*m+1) & 3], src, 64);
      float w0 = hi ? b0 : a0;
      float w1 = hi ? b1 : a1;
      #pragma unroll
      for (int r = 0; r < 4; ++r){
        vA[4*m+r] = acc[m][0][r]*w0 + acc[m][1][r]*w1;
        vM[4*m+r] = fmaxf(acc[m][0][r]*gm0, acc[m][1][r]*gm1);
      }
    }
    #pragma unroll
    for (int s = 0; s < 4; ++s){
      const int mm = 8 >> s;
      const bool up = (l15 & mm) != 0;
      #pragma unroll
      for (int k2 = 0; k2 < mm; ++k2){
        float sendA = up ? vA[k2] : vA[k2 + mm];
        float keepA = up ? vA[k2 + mm] : vA[k2];
        vA[k2] = keepA + __shfl_xor(sendA, mm, 64);
        float sendM = up ? vM[k2] : vM[k2 + mm];
        float keepM = up ? vM[k2 + mm] : vM[k2];
        vM[k2] = fmaxf(keepM, __shfl_xor(sendM, mm, 64));
      }
    }
    outb[4*it] = vA[0] + vM[0];
  }
}

extern "C" void kernel_launch(void* const* d_in, const int* in_sizes, int n_in,
                              void* d_out, int out_size, void* d_ws, size_t ws_size,
                              hipStream_t stream){
  (void)in_sizes; (void)n_in; (void)out_size; (void)ws_size;
  gsl_prep<<<dim3(1), dim3(512), 0, stream>>>(
    (const float*)d_in[11], (const float*)d_in[16], (const float*)d_in[23],
    (const float*)d_in[7],  (const float*)d_in[9],  (const float*)d_in[10],
    (const float*)d_in[8],  (const float*)d_in[2],  (const float*)d_in[21],
    (const float*)d_in[28], (const float*)d_in[29], (char*)d_ws);
  gsl_fused<<<dim3(1024), dim3(256), 0, stream>>>(
    (const float*)d_in[0],  (const float*)d_in[1],  (const float*)d_in[3],
    (const float*)d_in[4],  (const float*)d_in[5],  (const float*)d_in[6],
    (const float*)d_in[8],  (const float*)d_in[12], (const float*)d_in[13],
    (const float*)d_in[14], (const float*)d_in[15], (const float*)d_in[17],
    (const float*)d_in[18], (const float*)d_in[19], (const float*)d_in[20],
    (const float*)d_in[22], (const float*)d_in[24], (const float*)d_in[25],
    (const float*)d_in[26], (const float*)d_in[27], (const char*)d_ws,
    (float*)d_out);
}

// Round 13
// 254.293 us; speedup vs baseline: 1.0365x; 1.0365x over previous
//
#include <hip/hip_runtime.h>

// Grouped_Soft_GSL_Block_PE fused kernel for MI355X (gfx950).
// B=8, IC2=128, N=2048, K=32, C=64, G=8, CPG=8, hidden=16.
// R13: 3-blocks/CU attempt with engineered arch-VGPR budget.
// 1024 blocks x 16 n (4 iters of 4 n), 256 thr / 4 waves; wave wv owns
// n = nblk+4it+wv; zero barriers in loop. Weights pre-packed in d_ws
// (L1/L2-hot); LDS = xbuf+tabs = 36.9KB. HALF-TILE prefetch: only fa
// (chans 0..63, 32 f32 regs) carried across iters; fb issued mid-iteration
// after GEMM-half-1's A-frag loads (in-order vmcnt: GEMM1's A-wait does
// not chain behind fb). Accumulators in AGPRs; arch peak ~95 regs.

typedef __attribute__((ext_vector_type(8))) short bf16x8;
typedef __attribute__((ext_vector_type(4))) float f32x4;

#define EPS_BN 1e-5f

// d_ws byte offsets
#define WSA   0        // main A-frags [m*4+ks][lane] 24*1024 = 24576
#define WSP   24576    // pos2 frags [m2*2+ks][lane] 8*1024 = 8192
#define WSPE  32768    // peW2 frags [ks][lane] 2*1024 = 2048
#define WSPW1 34816    // pos_w1 packed [m2][lane] uint2 = 2048
#define WSGAF 36864    // gate/attn-2 frag [lane] = 1024
#define WSLCR 37888    // combined logit consts [16] f32 = 64

__device__ __forceinline__ unsigned pk2(float a, float b){
  unsigned ua = __float_as_uint(a) + 0x8000u;
  unsigned ub = __float_as_uint(b) + 0x8000u;
  return __builtin_amdgcn_perm(ub, ua, 0x07060302);
}
__device__ __forceinline__ float lrelu(float v){ return fmaxf(v, 0.2f*v); }

// DPP row_ror reductions over the 16-lane row (l15 = k dimension)
template<int N>
__device__ __forceinline__ float ror16(float x){
  return __int_as_float(__builtin_amdgcn_mov_dpp(__float_as_int(x), 0x120+N, 0xF, 0xF, false));
}
__device__ __forceinline__ float rsum16(float v){
  v += ror16<1>(v); v += ror16<2>(v); v += ror16<4>(v); v += ror16<8>(v); return v;
}
__device__ __forceinline__ float rmax16(float v){
  v = fmaxf(v, ror16<1>(v)); v = fmaxf(v, ror16<2>(v));
  v = fmaxf(v, ror16<4>(v)); v = fmaxf(v, ror16<8>(v)); return v;
}

#define MFMA16(a,b,c) __builtin_amdgcn_mfma_f32_16x16x32_bf16((a),(b),(c),0,0,0)

__global__ void gsl_prep(const float* __restrict__ trans_w, const float* __restrict__ gate_w1,
                         const float* __restrict__ attn_w1, const float* __restrict__ pos_w2,
                         const float* __restrict__ pe_w,    const float* __restrict__ pe_b,
                         const float* __restrict__ pos_b2,  const float* __restrict__ pos_w1,
                         const float* __restrict__ gate_w2, const float* __restrict__ attn_w2,
                         const float* __restrict__ attn_b2, char* __restrict__ ws){
  const int t = threadIdx.x;   // 512 threads
  for (int idx = t; idx < 1536; idx += 512){
    int id = idx >> 6, lane = idx & 63;
    int m = id >> 2, ks = id & 3, l15 = lane & 15, g4 = lane >> 4;
    const float* src = (m < 4)  ? (trans_w + (16*m + l15)*128)
                     : (m == 4) ? (gate_w1 + l15*128)
                                : (attn_w1 + l15*128);
    src += 32*ks + 8*g4;
    uint4 u;
    u.x = pk2(src[0],src[1]); u.y = pk2(src[2],src[3]);
    u.z = pk2(src[4],src[5]); u.w = pk2(src[6],src[7]);
    *(uint4*)(ws + WSA + idx*16) = u;
  }
  {
    int id = t >> 6, lane = t & 63, l15 = lane & 15, g4 = lane >> 4;
    const float* src = pos_w2 + (16*(id>>1) + l15)*64 + 32*(id&1) + 8*g4;
    uint4 u;
    u.x = pk2(src[0],src[1]); u.y = pk2(src[2],src[3]);
    u.z = pk2(src[4],src[5]); u.w = pk2(src[6],src[7]);
    *(uint4*)(ws + WSP + t*16) = u;
  }
  if (t < 128){
    int ks = t >> 6, lane = t & 63, l15 = lane & 15, g4 = lane >> 4;
    uint4 u = make_uint4(0u,0u,0u,0u);
    if (l15 < 8){
      float w[8];
      #pragma unroll
      for (int j = 0; j < 8; ++j){
        int c = 32*ks + 8*g4 + j;
        float s = 0.f;
        for (int k = 0; k < 64; ++k) s += pe_w[l15*64 + k] * pos_w2[k*64 + c];
        w[j] = s;
      }
      u.x = pk2(w[0],w[1]); u.y = pk2(w[2],w[3]);
      u.z = pk2(w[4],w[5]); u.w = pk2(w[6],w[7]);
    }
    *(uint4*)(ws + WSPE + t*16) = u;
  }
  if (t < 256){
    int m2 = t >> 6, lane = t & 63, l15 = lane & 15, g4 = lane >> 4;
    uint2 u = make_uint2(0u, 0u);
    if (g4 == 0){
      const float* rp = pos_w1 + (16*m2 + l15)*3;
      u.x = pk2(rp[0], rp[1]); u.y = pk2(rp[2], 0.f);
    }
    *(uint2*)(ws + WSPW1 + t*8) = u;
  }
  if (t < 64){
    int l15 = t & 15, g4 = t >> 4;
    float v[8];
    #pragma unroll
    for (int j = 0; j < 8; ++j){
      int k = 8*g4 + j;
      float v2 = 0.f;
      if (l15 < 8)       { if (k >= 16) v2 = attn_w2[l15*16 + (k-16)]; }
      else if (l15 == 8) { if (k < 16)  v2 = gate_w2[k]; }
      v[j] = v2;
    }
    uint4 u;
    u.x = pk2(v[0],v[1]); u.y = pk2(v[2],v[3]);
    u.z = pk2(v[4],v[5]); u.w = pk2(v[6],v[7]);
    *(uint4*)(ws + WSGAF + t*16) = u;
  }
  if (t < 16){
    float v = 0.f;
    if (t < 8){
      v = pe_b[t] + attn_b2[t];
      for (int c = 0; c < 64; ++c) v += pe_w[t*64 + c] * pos_b2[c];
    }
    *(float*)(ws + WSLCR + t*4) = v;
  }
}

__global__ __launch_bounds__(256, 3)
void gsl_fused(const float* __restrict__ x,      const float* __restrict__ rel_pos,
               const float* __restrict__ pos_g,  const float* __restrict__ pos_bb,
               const float* __restrict__ pos_m,  const float* __restrict__ pos_v,
               const float* __restrict__ pos_b2, const float* __restrict__ tr_g,
               const float* __restrict__ tr_bb,  const float* __restrict__ tr_m,
               const float* __restrict__ tr_v,   const float* __restrict__ ga_g,
               const float* __restrict__ ga_bb,  const float* __restrict__ ga_m,
               const float* __restrict__ ga_v,   const float* __restrict__ gate_b2,
               const float* __restrict__ at_g,   const float* __restrict__ at_bb,
               const float* __restrict__ at_m,   const float* __restrict__ at_v,
               const char* __restrict__ ws,      float* __restrict__ out)
{
  // LDS map (36608 B, 3 blocks/CU LDS-wise):
  // [0,34816)      xbuf [128 cols][136] bf16 (16B-aligned rows, b128 frag
  //                reads); wave slice 8704B at wv*8704, aliased post-GEMM:
  //                h1b [32][72] @0, gab [32][40] @4608
  // [34816,36608)  tabs f32: trQ[256] (s,b,pos_b2,0) p1T[128] gaT[32] atT[32]
  __shared__ __align__(16) char smem[36608];
  short* xbuf = (short*)smem;
  float* trQ  = (float*)(smem + 34816);
  float* p1T  = (float*)(smem + 35840);
  float* gaT  = (float*)(smem + 36352);
  float* atT  = (float*)(smem + 36480);

  const int tid = threadIdx.x;
  const int wv  = tid >> 6;
  const int l   = tid & 63;
  const int l15 = l & 15, g4 = l >> 4;
  const int bid = blockIdx.x;
  const int b    = bid >> 7;           // 128 blocks per batch
  const int nblk = (bid & 127) << 4;   // 16 n per block

  // ---- BN fold tables ----
  if (tid < 64){
    float s = tr_g[tid] * rsqrtf(tr_v[tid] + EPS_BN);
    *(float4*)(trQ + 4*tid) = make_float4(s, tr_bb[tid] - tr_m[tid]*s, pos_b2[tid], 0.f);
    float s2 = pos_g[tid] * rsqrtf(pos_v[tid] + EPS_BN);
    p1T[2*tid] = s2; p1T[2*tid+1] = pos_bb[tid] - pos_m[tid]*s2;
  } else if (tid < 80){
    int c = tid - 64;
    float s = ga_g[c] * rsqrtf(ga_v[c] + EPS_BN);
    gaT[2*c] = s; gaT[2*c+1] = ga_bb[c] - ga_m[c]*s;
  } else if (tid < 96){
    int c = tid - 80;
    float s = at_g[c] * rsqrtf(at_v[c] + EPS_BN);
    atT[2*c] = s; atT[2*c+1] = at_bb[c] - at_m[c]*s;
  }

  // ---- persistent small frags / consts from ws ----
  uint2 pw1p[4];
  #pragma unroll
  for (int m2 = 0; m2 < 4; ++m2)
    pw1p[m2] = *(const uint2*)(ws + WSPW1 + (m2*64 + l)*8);
  bf16x8 gaf = *(const bf16x8*)(ws + WSGAF + l*16);
  float lcr[4];
  #pragma unroll
  for (int r = 0; r < 4; ++r)
    lcr[r] = *(const float*)(ws + WSLCR + (4*g4 + r)*4);
  const float gb2v = gate_b2[0];

  // ---- per-wave constants ----
  const int col0 = 32*wv + l15, col1 = col0 + 16;
  const int lc0 = l15, lc1 = l15 + 16;
  const int lq = l & 7, ld = l >> 3;
  const int colb = 32*wv + 4*lq;
  char*  slice = smem + wv*8704;
  short* h1b   = (short*)slice;            // [32][72]
  short* gab   = (short*)(slice + 4608);   // [32][40]
  const float* xp0 = x + (((long)(b*128 + 8*ld)) << 16) + colb;
  const float* rpb = rel_pos + (((long)(3*b)) << 16);
  const int och = 16*(l15 >> 2) + 4*g4 + (l15 & 3);
  float* outb = out + (((long)(b*64 + och)) << 11) + nblk + wv;

  // ---- prologue: half-A prefetch (chans 0..63) + rel for iter 0 ----
  f32x4 fa[8];
  float rc[6] = {0.f,0.f,0.f,0.f,0.f,0.f};
  {
    const long sb0 = (long)nblk * 32;
    #pragma unroll
    for (int j = 0; j < 8; ++j) fa[j] = *(const f32x4*)(xp0 + sb0 + (((long)j) << 16));
    if (g4 == 0){
      long sg = sb0 + col0;
      rc[0] = rpb[sg];          rc[1] = rpb[sg + 65536];      rc[2] = rpb[sg + 131072];
      rc[3] = rpb[sg + 16];     rc[4] = rpb[sg + 65536 + 16]; rc[5] = rpb[sg + 131072 + 16];
    }
  }

  __syncthreads();   // tabs visible

  for (int it = 0; it < 4; ++it){
    const long sbase = (long)nblk*32 + 128*it;

    // (1) cvt + write half A (chans 0..63) from carried fa
    #pragma unroll
    for (int i2 = 0; i2 < 4; ++i2){
      short* dst = xbuf + (colb+i2)*136 + 8*ld;
      *(uint2*)(dst)     = make_uint2(pk2(fa[0][i2],fa[1][i2]), pk2(fa[2][i2],fa[3][i2]));
      *(uint2*)(dst + 4) = make_uint2(pk2(fa[4][i2],fa[5][i2]), pk2(fa[6][i2],fa[7][i2]));
    }

    // (2) GEMM half 1 (ks=0,1): A-frags from ws issue BEFORE fb
    f32x4 acc[6][2];
    #pragma unroll
    for (int m = 0; m < 6; ++m){
      f32x4 z = {0.f,0.f,0.f,0.f};
      acc[m][0] = z; acc[m][1] = z;
    }
    #pragma unroll
    for (int ks = 0; ks < 2; ++ks){
      bf16x8 b0 = *(const bf16x8*)(xbuf + col0*136 + 32*ks + 8*g4);
      bf16x8 b1 = *(const bf16x8*)(xbuf + col1*136 + 32*ks + 8*g4);
      #pragma unroll
      for (int m = 0; m < 6; ++m){
        bf16x8 af = *(const bf16x8*)(ws + WSA + (((m<<2)|ks)*64 + l)*16);
        acc[m][0] = MFMA16(af, b0, acc[m][0]);
        acc[m][1] = MFMA16(af, b1, acc[m][1]);
      }
    }

    // (3) half B loads (chans 64..127) — issued after GEMM1's A-frags
    f32x4 fbv[8];
    #pragma unroll
    for (int j = 0; j < 8; ++j) fbv[j] = *(const f32x4*)(xp0 + sbase + (((long)(64+j)) << 16));

    // (4) cvt + write half B (waits fb arrival)
    #pragma unroll
    for (int i2 = 0; i2 < 4; ++i2){
      short* dst = xbuf + (colb+i2)*136 + 64 + 8*ld;
      *(uint2*)(dst)     = make_uint2(pk2(fbv[0][i2],fbv[1][i2]), pk2(fbv[2][i2],fbv[3][i2]));
      *(uint2*)(dst + 4) = make_uint2(pk2(fbv[4][i2],fbv[5][i2]), pk2(fbv[6][i2],fbv[7][i2]));
    }

    // (5) GEMM half 2 (ks=2,3)
    #pragma unroll
    for (int ks = 2; ks < 4; ++ks){
      bf16x8 b0 = *(const bf16x8*)(xbuf + col0*136 + 32*ks + 8*g4);
      bf16x8 b1 = *(const bf16x8*)(xbuf + col1*136 + 32*ks + 8*g4);
      #pragma unroll
      for (int m = 0; m < 6; ++m){
        bf16x8 af = *(const bf16x8*)(ws + WSA + (((m<<2)|ks)*64 + l)*16);
        acc[m][0] = MFMA16(af, b0, acc[m][0]);
        acc[m][1] = MFMA16(af, b1, acc[m][1]);
      }
    }

    // (6) pos layer 1 (K padded 3->32) -> h1b ; uses rc of CURRENT iter
    {
      bf16x8 rf0 = {0,0,0,0,0,0,0,0}, rf1 = {0,0,0,0,0,0,0,0};
      if (g4 == 0){
        union { bf16x8 v; unsigned u[4]; } t0, t1;
        t0.u[0] = pk2(rc[0], rc[1]); t0.u[1] = pk2(rc[2], 0.f); t0.u[2] = 0u; t0.u[3] = 0u;
        t1.u[0] = pk2(rc[3], rc[4]); t1.u[1] = pk2(rc[5], 0.f); t1.u[2] = 0u; t1.u[3] = 0u;
        rf0 = t0.v; rf1 = t1.v;
      }
      #pragma unroll
      for (int m2 = 0; m2 < 4; ++m2){
        union { bf16x8 v; unsigned u[4]; } aw;
        aw.u[0] = pw1p[m2].x; aw.u[1] = pw1p[m2].y; aw.u[2] = 0u; aw.u[3] = 0u;
        f32x4 z = {0.f,0.f,0.f,0.f};
        f32x4 d0 = MFMA16(aw.v, rf0, z);
        f32x4 d1 = MFMA16(aw.v, rf1, z);
        int cb2 = 16*m2 + 4*g4;
        float2 t0 = *(const float2*)(p1T + 2*(cb2+0));
        float2 t1 = *(const float2*)(p1T + 2*(cb2+1));
        float2 t2 = *(const float2*)(p1T + 2*(cb2+2));
        float2 t3 = *(const float2*)(p1T + 2*(cb2+3));
        float h0 = lrelu(t0.x*d0[0]+t0.y), h1v = lrelu(t1.x*d0[1]+t1.y);
        float h2 = lrelu(t2.x*d0[2]+t2.y), h3 = lrelu(t3.x*d0[3]+t3.y);
        *(uint2*)(h1b + lc0*72 + cb2) = make_uint2(pk2(h0,h1v), pk2(h2,h3));
        h0 = lrelu(t0.x*d1[0]+t0.y); h1v = lrelu(t1.x*d1[1]+t1.y);
        h2 = lrelu(t2.x*d1[2]+t2.y); h3 = lrelu(t3.x*d1[3]+t3.y);
        *(uint2*)(h1b + lc1*72 + cb2) = make_uint2(pk2(h0,h1v), pk2(h2,h3));
      }
    }

    // (7) trans epilogue: acc[0..3] = lrelu(BN(conv)) + pos_b2
    #pragma unroll
    for (int m = 0; m < 4; ++m)
      #pragma unroll
      for (int r = 0; r < 4; ++r){
        float4 tq = *(const float4*)(trQ + 4*(16*m + 4*g4 + r));
        acc[m][0][r] = lrelu(tq.x*acc[m][0][r] + tq.y) + tq.z;
        acc[m][1][r] = lrelu(tq.x*acc[m][1][r] + tq.y) + tq.z;
      }

    // (8) pos2 MFMAs accumulate INTO acc[0..3]; pe-fold -> pac4 (ws frags)
    f32x4 pac4[2];
    {
      f32x4 z = {0.f,0.f,0.f,0.f};
      pac4[0] = z; pac4[1] = z;
    }
    #pragma unroll
    for (int ks = 0; ks < 2; ++ks){
      bf16x8 h0 = *(const bf16x8*)(h1b + lc0*72 + 32*ks + 8*g4);
      bf16x8 h1v = *(const bf16x8*)(h1b + lc1*72 + 32*ks + 8*g4);
      #pragma unroll
      for (int m2 = 0; m2 < 4; ++m2){
        bf16x8 af = *(const bf16x8*)(ws + WSP + ((m2*2 + ks)*64 + l)*16);
        acc[m2][0] = MFMA16(af, h0, acc[m2][0]);
        acc[m2][1] = MFMA16(af, h1v, acc[m2][1]);
      }
      bf16x8 af4 = *(const bf16x8*)(ws + WSPE + (ks*64 + l)*16);
      pac4[0] = MFMA16(af4, h0, pac4[0]);
      pac4[1] = MFMA16(af4, h1v, pac4[1]);
    }

    // (9) hidden epilogues -> gab (gate_h ch 0..15, attn_h ch 16..31)
    {
      int hc = 4*g4;
      float2 g0p = *(const float2*)(gaT + 2*(hc+0));
      float2 g1p = *(const float2*)(gaT + 2*(hc+1));
      float2 g2p = *(const float2*)(gaT + 2*(hc+2));
      float2 g3p = *(const float2*)(gaT + 2*(hc+3));
      float2 a0p = *(const float2*)(atT + 2*(hc+0));
      float2 a1p = *(const float2*)(atT + 2*(hc+1));
      float2 a2p = *(const float2*)(atT + 2*(hc+2));
      float2 a3p = *(const float2*)(atT + 2*(hc+3));
      #pragma unroll
      for (int ct = 0; ct < 2; ++ct){
        int lc = (ct == 0) ? lc0 : lc1;
        float q0 = lrelu(g0p.x*acc[4][ct][0] + g0p.y), q1 = lrelu(g1p.x*acc[4][ct][1] + g1p.y);
        float q2 = lrelu(g2p.x*acc[4][ct][2] + g2p.y), q3 = lrelu(g3p.x*acc[4][ct][3] + g3p.y);
        *(uint2*)(gab + lc*40 + hc) = make_uint2(pk2(q0,q1), pk2(q2,q3));
        float a0 = lrelu(a0p.x*acc[5][ct][0] + a0p.y), a1 = lrelu(a1p.x*acc[5][ct][1] + a1p.y);
        float a2 = lrelu(a2p.x*acc[5][ct][2] + a2p.y), a3 = lrelu(a3p.x*acc[5][ct][3] + a3p.y);
        *(uint2*)(gab + lc*40 + 16 + hc) = make_uint2(pk2(a0,a1), pk2(a2,a3));
      }
    }

    // (10) gate/attn layer-2 MFMA (rows 0..7 attn, row 8 gate)
    f32x4 gac0 = {0.f,0.f,0.f,0.f}, gac1 = gac0;
    {
      bf16x8 g0 = *(const bf16x8*)(gab + lc0*40 + 8*g4);
      bf16x8 g1 = *(const bf16x8*)(gab + lc1*40 + 8*g4);
      gac0 = MFMA16(gaf, g0, gac0);
      gac1 = MFMA16(gaf, g1, gac1);
    }

    // (11) issue fa + rel for NEXT iter (covered by softmax/butterfly/loop)
    if (it < 3){
      const long nsb = sbase + 128;
      #pragma unroll
      for (int j = 0; j < 8; ++j) fa[j] = *(const f32x4*)(xp0 + nsb + (((long)j) << 16));
      if (g4 == 0){
        long sg = nsb + col0;
        rc[0] = rpb[sg];          rc[1] = rpb[sg + 65536];      rc[2] = rpb[sg + 131072];
        rc[3] = rpb[sg + 16];     rc[4] = rpb[sg + 65536 + 16]; rc[5] = rpb[sg + 131072 + 16];
      }
    }

    // (12) gate + logits + softmax over k (DPP reduce)
    float gv0 = __shfl(gac0[0], 32 + l15, 64);
    float gv1 = __shfl(gac1[0], 32 + l15, 64);
    float gm0 = 1.f/(1.f + __expf(-(gv0 + gb2v)));
    float gm1 = 1.f/(1.f + __expf(-(gv1 + gb2v)));
    float lg0 = __logf(gm0 + 1e-6f), lg1 = __logf(gm1 + 1e-6f);

    float wg0[4], wg1[4];
    #pragma unroll
    for (int r = 0; r < 4; ++r){
      float t0 = gac0[r] + pac4[0][r] + lcr[r] + lg0;
      float t1 = gac1[r] + pac4[1][r] + lcr[r] + lg1;
      float mx = rmax16(fmaxf(t0, t1));
      float e0 = __expf(t0 - mx), e1 = __expf(t1 - mx);
      float inv = 1.f / rsum16(e0 + e1);
      wg0[r] = e0 * inv; wg1[r] = e1 * inv;
    }

    // (13) vA/vM fill + reduce-scatter butterfly; one 64-lane store
    float vA[16], vM[16];
    const bool hi = (g4 >= 2);
    #pragma unroll
    for (int m = 0; m < 4; ++m){
      int src = 16*(m >> 1) + l15;
      float a0 = __shfl(wg0[(2*m) & 3],   src, 64);
      float b0 = __shfl(wg0[(2*m+1) & 3], src, 64);
      float a1 = __shfl(wg1[(2*m) & 3],   src, 64);
      float b1 = __shfl(wg1[(2*m+1) & 3], src, 64);
      float w0 = hi ? b0 : a0;
      float w1 = hi ? b1 : a1;
      #pragma unroll
      for (int r = 0; r < 4; ++r){
        vA[4*m+r] = acc[m][0][r]*w0 + acc[m][1][r]*w1;
        vM[4*m+r] = fmaxf(acc[m][0][r]*gm0, acc[m][1][r]*gm1);
      }
    }
    #pragma unroll
    for (int s = 0; s < 4; ++s){
      const int mm = 8 >> s;
      const bool up = (l15 & mm) != 0;
      #pragma unroll
      for (int k2 = 0; k2 < mm; ++k2){
        float sendA = up ? vA[k2] : vA[k2 + mm];
        float keepA = up ? vA[k2 + mm] : vA[k2];
        vA[k2] = keepA + __shfl_xor(sendA, mm, 64);
        float sendM = up ? vM[k2] : vM[k2 + mm];
        float keepM = up ? vM[k2 + mm] : vM[k2];
        vM[k2] = fmaxf(keepM, __shfl_xor(sendM, mm, 64));
      }
    }
    outb[4*it] = vA[0] + vM[0];
  }
}

extern "C" void kernel_launch(void* const* d_in, const int* in_sizes, int n_in,
                              void* d_out, int out_size, void* d_ws, size_t ws_size,
                              hipStream_t stream){
  (void)in_sizes; (void)n_in; (void)out_size; (void)ws_size;
  gsl_prep<<<dim3(1), dim3(512), 0, stream>>>(
    (const float*)d_in[11], (const float*)d_in[16], (const float*)d_in[23],
    (const float*)d_in[7],  (const float*)d_in[9],  (const float*)d_in[10],
    (const float*)d_in[8],  (const float*)d_in[2],  (const float*)d_in[21],
    (const float*)d_in[28], (const float*)d_in[29], (char*)d_ws);
  gsl_fused<<<dim3(1024), dim3(256), 0, stream>>>(
    (const float*)d_in[0],  (const float*)d_in[1],  (const float*)d_in[3],
    (const float*)d_in[4],  (const float*)d_in[5],  (const float*)d_in[6],
    (const float*)d_in[8],  (const float*)d_in[12], (const float*)d_in[13],
    (const float*)d_in[14], (const float*)d_in[15], (const float*)d_in[17],
    (const float*)d_in[18], (const float*)d_in[19], (const float*)d_in[20],
    (const float*)d_in[22], (const float*)d_in[24], (const float*)d_in[25],
    (const float*)d_in[26], (const float*)d_in[27], (const char*)d_ws,
    (float*)d_out);
}

// Round 14
// 76.048 us; speedup vs baseline: 3.4659x; 3.3439x over previous
//
#include <hip/hip_runtime.h>

// Grouped_Soft_GSL_Block_PE fused kernel for MI355X (gfx950).
// B=8, IC2=128, N=2048, K=32, C=64, G=8, CPG=8, hidden=16.
// R14: R11 structure (2 blocks/CU, 256 thr / 4 waves, zero barriers in loop,
// bank-optimal strides 132/68/36, butterfly epilogue, prep kernel for
// peW2/peBt) with grid split 512x32n -> 1024x16n (4 iters): 2 resident +
// 2 queued blocks per CU so preamble/drain of one block overlaps the
// co-resident block's main loop (block-level backfill).

typedef __attribute__((ext_vector_type(8))) short bf16x8;
typedef __attribute__((ext_vector_type(4))) float f32x4;

#define EPS_BN 1e-5f

__device__ __forceinline__ unsigned pk2(float a, float b){
  unsigned ua = __float_as_uint(a) + 0x8000u;
  unsigned ub = __float_as_uint(b) + 0x8000u;
  return __builtin_amdgcn_perm(ub, ua, 0x07060302);
}
__device__ __forceinline__ short f2bf(float a){
  unsigned u = __float_as_uint(a);
  u += 0x7FFFu + ((u >> 16) & 1u);
  return (short)(u >> 16);
}
__device__ __forceinline__ float lrelu(float v){ return fmaxf(v, 0.2f*v); }

__device__ __forceinline__ void st8(short* dst, float4 a, float4 b){
  *(uint2*)(dst)     = make_uint2(pk2(a.x,a.y), pk2(a.z,a.w));
  *(uint2*)(dst + 4) = make_uint2(pk2(b.x,b.y), pk2(b.z,b.w));
}
__device__ __forceinline__ bf16x8 ld8(const short* p){
  union { bf16x8 v; uint2 q[2]; } w;
  w.q[0] = *(const uint2*)(p);
  w.q[1] = *(const uint2*)(p + 4);
  return w.v;
}

// DPP row_ror reductions over the 16-lane row (l15 = k dimension)
template<int N>
__device__ __forceinline__ float ror16(float x){
  return __int_as_float(__builtin_amdgcn_mov_dpp(__float_as_int(x), 0x120+N, 0xF, 0xF, false));
}
__device__ __forceinline__ float rsum16(float v){
  v += ror16<1>(v); v += ror16<2>(v); v += ror16<4>(v); v += ror16<8>(v); return v;
}
__device__ __forceinline__ float rmax16(float v){
  v = fmaxf(v, ror16<1>(v)); v = fmaxf(v, ror16<2>(v));
  v = fmaxf(v, ror16<4>(v)); v = fmaxf(v, ror16<8>(v)); return v;
}

#define MFMA16(a,b,c) __builtin_amdgcn_mfma_f32_16x16x32_bf16((a),(b),(c),0,0,0)

// prep: peW2 = pe_w @ pos_w2 (8x64, row-major) -> ws[0..511]; peBt -> ws[512..527]
__global__ void gsl_prep(const float* __restrict__ pos_w2, const float* __restrict__ pe_w,
                         const float* __restrict__ pe_b,   const float* __restrict__ pos_b2,
                         float* __restrict__ ws){
  int t = threadIdx.x;            // 0..511
  int r = t >> 6, j = t & 63;
  float s = 0.f;
  for (int c = 0; c < 64; ++c) s += pe_w[r*64 + c] * pos_w2[c*64 + j];
  ws[t] = s;
  if (t < 16){
    float v = 0.f;
    if (t < 8){
      v = pe_b[t];
      for (int c = 0; c < 64; ++c) v += pe_w[t*64 + c] * pos_b2[c];
    }
    ws[512 + t] = v;
  }
}

__global__ __launch_bounds__(256, 2)
void gsl_fused(const float* __restrict__ x,       const float* __restrict__ rel_pos,
               const float* __restrict__ pos_w1,  const float* __restrict__ pos_g,
               const float* __restrict__ pos_bb,  const float* __restrict__ pos_m,
               const float* __restrict__ pos_v,   const float* __restrict__ pos_w2,
               const float* __restrict__ pos_b2,  const float* __restrict__ trans_w,
               const float* __restrict__ tr_g,    const float* __restrict__ tr_bb,
               const float* __restrict__ tr_m,    const float* __restrict__ tr_v,
               const float* __restrict__ gate_w1, const float* __restrict__ ga_g,
               const float* __restrict__ ga_bb,   const float* __restrict__ ga_m,
               const float* __restrict__ ga_v,    const float* __restrict__ gate_w2,
               const float* __restrict__ gate_b2, const float* __restrict__ attn_w1,
               const float* __restrict__ at_g,    const float* __restrict__ at_bb,
               const float* __restrict__ at_m,    const float* __restrict__ at_v,
               const float* __restrict__ attn_w2, const float* __restrict__ attn_b2,
               const float* __restrict__ ws,      float* __restrict__ out)
{
  // LDS map (70784 B, 2 blocks/CU):
  // [0,33792)      xbuf [128 cols][132] bf16; wave slice 8448B at wv*8448,
  //                aliased post-GEMM per wave: h1b [32][68] @0, gab [32][36] @4352
  // [33792,59136)  wmain [96][132] bf16 (trans 0..63, gate 64..79, attn 80..95)
  // [59136,68928)  wpos2 [72][68] bf16 (rows 0..63 pos_w2; 64..71 peW2 from ws)
  // [68928,70784)  tabs f32: trQ[256] (s,b,pos_b2,0 quads) p1T[128] gaT[32] atT[32]
  __shared__ __align__(16) char smem[70784];
  short* xbuf  = (short*)smem;
  short* wmain = (short*)(smem + 33792);
  short* wpos2 = (short*)(smem + 59136);
  float* trQ  = (float*)(smem + 68928);
  float* p1T  = (float*)(smem + 69952);
  float* gaT  = (float*)(smem + 70464);
  float* atT  = (float*)(smem + 70592);

  const int tid = threadIdx.x;
  const int wv  = tid >> 6;
  const int l   = tid & 63;
  const int l15 = l & 15, g4 = l >> 4;
  const int bid = blockIdx.x;
  const int b    = bid >> 7;           // 128 blocks per batch
  const int nblk = (bid & 127) << 4;   // 16 n per block

  // ---- stage weights -> LDS bf16 ----
  if (tid < 192){
    int r = tid >> 1, c0 = (tid & 1) * 64;
    const float* src = (r < 64) ? (trans_w + r*128)
                     : (r < 80) ? (gate_w1 + (r-64)*128)
                                : (attn_w1 + (r-80)*128);
    src += c0;
    short* dst = wmain + r*132 + c0;
    #pragma unroll
    for (int j = 0; j < 8; ++j)
      st8(dst + 8*j, *(const float4*)(src + 8*j), *(const float4*)(src + 8*j + 4));
  } else {
    int r = tid - 192;
    const float* src = pos_w2 + r*64;
    short* dst = wpos2 + r*68;
    #pragma unroll
    for (int j = 0; j < 8; ++j)
      st8(dst + 8*j, *(const float4*)(src + 8*j), *(const float4*)(src + 8*j + 4));
  }
  // peW2 rows 64..71 of wpos2 from ws
  if (tid < 16){
    int r = tid >> 1, c0 = (tid & 1) * 32;
    const float* src = ws + r*64 + c0;
    short* dst = wpos2 + (64 + r)*68 + c0;
    #pragma unroll
    for (int j = 0; j < 4; ++j)
      st8(dst + 8*j, *(const float4*)(src + 8*j), *(const float4*)(src + 8*j + 4));
  }
  // ---- BN fold tables ----
  if (tid < 64){
    float s = tr_g[tid] * rsqrtf(tr_v[tid] + EPS_BN);
    *(float4*)(trQ + 4*tid) = make_float4(s, tr_bb[tid] - tr_m[tid]*s, pos_b2[tid], 0.f);
    float s2 = pos_g[tid] * rsqrtf(pos_v[tid] + EPS_BN);
    p1T[2*tid] = s2; p1T[2*tid+1] = pos_bb[tid] - pos_m[tid]*s2;
  } else if (tid < 80){
    int c = tid - 64;
    float s = ga_g[c] * rsqrtf(ga_v[c] + EPS_BN);
    gaT[2*c] = s; gaT[2*c+1] = ga_bb[c] - ga_m[c]*s;
  } else if (tid < 96){
    int c = tid - 80;
    float s = at_g[c] * rsqrtf(at_v[c] + EPS_BN);
    atT[2*c] = s; atT[2*c+1] = at_bb[c] - at_m[c]*s;
  }

  // ---- small weights / consts -> registers ----
  uint2 pw1p[4];
  #pragma unroll
  for (int m2 = 0; m2 < 4; ++m2){
    uint2 t = make_uint2(0u, 0u);
    if (g4 == 0){
      const float* rp = pos_w1 + (16*m2 + l15)*3;
      t.x = pk2(rp[0], rp[1]);
      t.y = pk2(rp[2], 0.f);
    }
    pw1p[m2] = t;
  }
  bf16x8 gaf;
  {
    bf16x8 t = {0,0,0,0,0,0,0,0};
    #pragma unroll
    for (int j = 0; j < 8; ++j){
      int k = 8*g4 + j;
      float v2 = 0.f;
      if (l15 < 8)       { if (k >= 16) v2 = attn_w2[l15*16 + (k-16)]; }
      else if (l15 == 8) { if (k < 16)  v2 = gate_w2[k]; }
      t[j] = f2bf(v2);
    }
    gaf = t;
  }
  const float gb2v = gate_b2[0];
  float lcr[4];      // attn_b2 + peBt combined logit const
  #pragma unroll
  for (int r = 0; r < 4; ++r){
    int row = 4*g4 + r;
    lcr[r] = ws[512 + row] + ((row < 8) ? attn_b2[row] : 0.f);
  }

  // ---- per-wave constants ----
  const int col0 = 32*wv + l15, col1 = col0 + 16;
  const int lc0 = l15, lc1 = l15 + 16;
  const int lq = l & 7, ld = l >> 3;
  const int colb = 32*wv + 4*lq;
  char*  slice = smem + wv*8448;
  short* h1b   = (short*)slice;            // [32][68]
  short* gab   = (short*)(slice + 4352);   // [32][36]
  const float* xp0 = x + (((long)(b*128 + 8*ld)) << 16) + colb;
  const float* rpb = rel_pos + (((long)(3*b)) << 16);
  const int och = 16*(l15 >> 2) + 4*g4 + (l15 & 3);   // butterfly output channel
  float* outb = out + (((long)(b*64 + och)) << 11) + nblk + wv;

  // ---- prologue: prefetch iteration 0 ----
  f32x4 fa[8], fb[8];
  float rc[6] = {0.f,0.f,0.f,0.f,0.f,0.f};
  {
    const long sb0 = (long)nblk * 32;
    #pragma unroll
    for (int j = 0; j < 8; ++j) fa[j] = *(const f32x4*)(xp0 + sb0 + (((long)j) << 16));
    #pragma unroll
    for (int j = 0; j < 8; ++j) fb[j] = *(const f32x4*)(xp0 + sb0 + (((long)(64+j)) << 16));
    if (g4 == 0){
      long sg = sb0 + col0;
      rc[0] = rpb[sg];          rc[1] = rpb[sg + 65536];      rc[2] = rpb[sg + 131072];
      rc[3] = rpb[sg + 16];     rc[4] = rpb[sg + 65536 + 16]; rc[5] = rpb[sg + 131072 + 16];
    }
  }

  __syncthreads();   // LDS weights + tables visible

  for (int it = 0; it < 4; ++it){
    const long sbase = (long)nblk*32 + 128*it;

    // (1) cvt + write staged tile -> own xbuf slice (consumes fa,fb)
    #pragma unroll
    for (int i2 = 0; i2 < 4; ++i2){
      short* dst = xbuf + (colb+i2)*132 + 8*ld;
      *(uint2*)(dst)      = make_uint2(pk2(fa[0][i2],fa[1][i2]), pk2(fa[2][i2],fa[3][i2]));
      *(uint2*)(dst + 4)  = make_uint2(pk2(fa[4][i2],fa[5][i2]), pk2(fa[6][i2],fa[7][i2]));
      *(uint2*)(dst + 64) = make_uint2(pk2(fb[0][i2],fb[1][i2]), pk2(fb[2][i2],fb[3][i2]));
      *(uint2*)(dst + 68) = make_uint2(pk2(fb[4][i2],fb[5][i2]), pk2(fb[6][i2],fb[7][i2]));
    }

    const long nsb = sbase + 128;
    // (2) prefetch fa half for next iter (in flight across GEMM)
    if (it < 3){
      #pragma unroll
      for (int j = 0; j < 8; ++j) fa[j] = *(const f32x4*)(xp0 + nsb + (((long)j) << 16));
    }

    // (3) main GEMM: [96x128] @ xtile
    f32x4 acc[6][2];
    #pragma unroll
    for (int m = 0; m < 6; ++m){
      f32x4 z = {0.f,0.f,0.f,0.f};
      acc[m][0] = z; acc[m][1] = z;
    }
    #pragma unroll
    for (int ks = 0; ks < 4; ++ks){
      bf16x8 b0 = ld8(xbuf + col0*132 + 32*ks + 8*g4);
      bf16x8 b1 = ld8(xbuf + col1*132 + 32*ks + 8*g4);
      #pragma unroll
      for (int m = 0; m < 6; ++m){
        bf16x8 af = ld8(wmain + (16*m + l15)*132 + 32*ks + 8*g4);
        acc[m][0] = MFMA16(af, b0, acc[m][0]);
        acc[m][1] = MFMA16(af, b1, acc[m][1]);
      }
    }

    // (4) prefetch fb half for next iter (in flight across epilogue)
    if (it < 3){
      #pragma unroll
      for (int j = 0; j < 8; ++j) fb[j] = *(const f32x4*)(xp0 + nsb + (((long)(64+j)) << 16));
    }

    // (5) pos layer 1 (K padded 3->32) -> h1b ; uses rc of CURRENT iter
    {
      bf16x8 rf0 = {0,0,0,0,0,0,0,0}, rf1 = {0,0,0,0,0,0,0,0};
      if (g4 == 0){
        union { bf16x8 v; unsigned u[4]; } t0, t1;
        t0.u[0] = pk2(rc[0], rc[1]); t0.u[1] = pk2(rc[2], 0.f); t0.u[2] = 0u; t0.u[3] = 0u;
        t1.u[0] = pk2(rc[3], rc[4]); t1.u[1] = pk2(rc[5], 0.f); t1.u[2] = 0u; t1.u[3] = 0u;
        rf0 = t0.v; rf1 = t1.v;
      }
      #pragma unroll
      for (int m2 = 0; m2 < 4; ++m2){
        union { bf16x8 v; unsigned u[4]; } aw;
        aw.u[0] = pw1p[m2].x; aw.u[1] = pw1p[m2].y; aw.u[2] = 0u; aw.u[3] = 0u;
        f32x4 z = {0.f,0.f,0.f,0.f};
        f32x4 d0 = MFMA16(aw.v, rf0, z);
        f32x4 d1 = MFMA16(aw.v, rf1, z);
        int cb2 = 16*m2 + 4*g4;
        float2 t0 = *(const float2*)(p1T + 2*(cb2+0));
        float2 t1 = *(const float2*)(p1T + 2*(cb2+1));
        float2 t2 = *(const float2*)(p1T + 2*(cb2+2));
        float2 t3 = *(const float2*)(p1T + 2*(cb2+3));
        float h0 = lrelu(t0.x*d0[0]+t0.y), h1v = lrelu(t1.x*d0[1]+t1.y);
        float h2 = lrelu(t2.x*d0[2]+t2.y), h3 = lrelu(t3.x*d0[3]+t3.y);
        *(uint2*)(h1b + lc0*68 + cb2) = make_uint2(pk2(h0,h1v), pk2(h2,h3));
        h0 = lrelu(t0.x*d1[0]+t0.y); h1v = lrelu(t1.x*d1[1]+t1.y);
        h2 = lrelu(t2.x*d1[2]+t2.y); h3 = lrelu(t3.x*d1[3]+t3.y);
        *(uint2*)(h1b + lc1*68 + cb2) = make_uint2(pk2(h0,h1v), pk2(h2,h3));
      }
    }
    // (5b) prefetch rel_pos for NEXT iter (after use)
    if (g4 == 0 && it < 3){
      long sg = nsb + col0;
      rc[0] = rpb[sg];          rc[1] = rpb[sg + 65536];      rc[2] = rpb[sg + 131072];
      rc[3] = rpb[sg + 16];     rc[4] = rpb[sg + 65536 + 16]; rc[5] = rpb[sg + 131072 + 16];
    }

    // (6) trans epilogue FIRST: acc[0..3] = lrelu(BN(conv)) + pos_b2
    #pragma unroll
    for (int m = 0; m < 4; ++m)
      #pragma unroll
      for (int r = 0; r < 4; ++r){
        float4 tq = *(const float4*)(trQ + 4*(16*m + 4*g4 + r));
        acc[m][0][r] = lrelu(tq.x*acc[m][0][r] + tq.y) + tq.z;
        acc[m][1][r] = lrelu(tq.x*acc[m][1][r] + tq.y) + tq.z;
      }

    // (7) pos2 MFMAs accumulate INTO acc[0..3]; pe-fold rows -> pac4
    f32x4 pac4[2];
    {
      f32x4 z = {0.f,0.f,0.f,0.f};
      pac4[0] = z; pac4[1] = z;
    }
    #pragma unroll
    for (int ks = 0; ks < 2; ++ks){
      bf16x8 h0 = ld8(h1b + lc0*68 + 32*ks + 8*g4);
      bf16x8 h1v = ld8(h1b + lc1*68 + 32*ks + 8*g4);
      #pragma unroll
      for (int m2 = 0; m2 < 4; ++m2){
        bf16x8 af = ld8(wpos2 + (16*m2 + l15)*68 + 32*ks + 8*g4);
        acc[m2][0] = MFMA16(af, h0, acc[m2][0]);
        acc[m2][1] = MFMA16(af, h1v, acc[m2][1]);
      }
      bf16x8 af4 = ld8(wpos2 + (64 + l15)*68 + 32*ks + 8*g4);
      pac4[0] = MFMA16(af4, h0, pac4[0]);
      pac4[1] = MFMA16(af4, h1v, pac4[1]);
    }

    // (8) hidden epilogues -> gab (gate_h ch 0..15, attn_h ch 16..31)
    {
      int hc = 4*g4;
      float2 g0p = *(const float2*)(gaT + 2*(hc+0));
      float2 g1p = *(const float2*)(gaT + 2*(hc+1));
      float2 g2p = *(const float2*)(gaT + 2*(hc+2));
      float2 g3p = *(const float2*)(gaT + 2*(hc+3));
      float2 a0p = *(const float2*)(atT + 2*(hc+0));
      float2 a1p = *(const float2*)(atT + 2*(hc+1));
      float2 a2p = *(const float2*)(atT + 2*(hc+2));
      float2 a3p = *(const float2*)(atT + 2*(hc+3));
      #pragma unroll
      for (int ct = 0; ct < 2; ++ct){
        int lc = (ct == 0) ? lc0 : lc1;
        float q0 = lrelu(g0p.x*acc[4][ct][0] + g0p.y), q1 = lrelu(g1p.x*acc[4][ct][1] + g1p.y);
        float q2 = lrelu(g2p.x*acc[4][ct][2] + g2p.y), q3 = lrelu(g3p.x*acc[4][ct][3] + g3p.y);
        *(uint2*)(gab + lc*36 + hc) = make_uint2(pk2(q0,q1), pk2(q2,q3));
        float a0 = lrelu(a0p.x*acc[5][ct][0] + a0p.y), a1 = lrelu(a1p.x*acc[5][ct][1] + a1p.y);
        float a2 = lrelu(a2p.x*acc[5][ct][2] + a2p.y), a3 = lrelu(a3p.x*acc[5][ct][3] + a3p.y);
        *(uint2*)(gab + lc*36 + 16 + hc) = make_uint2(pk2(a0,a1), pk2(a2,a3));
      }
    }

    // (9) gate/attn layer-2 MFMA (rows 0..7 attn, row 8 gate)
    f32x4 gac0 = {0.f,0.f,0.f,0.f}, gac1 = gac0;
    {
      bf16x8 g0 = ld8(gab + lc0*36 + 8*g4);
      bf16x8 g1 = ld8(gab + lc1*36 + 8*g4);
      gac0 = MFMA16(gaf, g0, gac0);
      gac1 = MFMA16(gaf, g1, gac1);
    }

    // (10) gate + logits + softmax over k (DPP reduce)
    float gv0 = __shfl(gac0[0], 32 + l15, 64);
    float gv1 = __shfl(gac1[0], 32 + l15, 64);
    float gm0 = 1.f/(1.f + __expf(-(gv0 + gb2v)));
    float gm1 = 1.f/(1.f + __expf(-(gv1 + gb2v)));
    float lg0 = __logf(gm0 + 1e-6f), lg1 = __logf(gm1 + 1e-6f);

    float wg0[4], wg1[4];
    #pragma unroll
    for (int r = 0; r < 4; ++r){
      float t0 = gac0[r] + pac4[0][r] + lcr[r] + lg0;
      float t1 = gac1[r] + pac4[1][r] + lcr[r] + lg1;
      float mx = rmax16(fmaxf(t0, t1));
      float e0 = __expf(t0 - mx), e1 = __expf(t1 - mx);
      float inv = 1.f / rsum16(e0 + e1);
      wg0[r] = e0 * inv; wg1[r] = e1 * inv;
    }

    // (11) fill vA/vM then reduce-scatter butterfly; one 64-lane store
    float vA[16], vM[16];
    const bool hi = (g4 >= 2);
    #pragma unroll
    for (int m = 0; m < 4; ++m){
      int src = 16*(m >> 1) + l15;
      float a0 = __shfl(wg0[(2*m) & 3],   src, 64);
      float b0 = __shfl(wg0[(2*m+1) & 3], src, 64);
      float a1 = __shfl(wg1[(2*m) & 3],   src, 64);
      float b1 = __shfl(wg1[(2*m+1) & 3], src, 64);
      float w0 = hi ? b0 : a0;
      float w1 = hi ? b1 : a1;
      #pragma unroll
      for (int r = 0; r < 4; ++r){
        vA[4*m+r] = acc[m][0][r]*w0 + acc[m][1][r]*w1;
        vM[4*m+r] = fmaxf(acc[m][0][r]*gm0, acc[m][1][r]*gm1);
      }
    }
    #pragma unroll
    for (int s = 0; s < 4; ++s){
      const int mm = 8 >> s;
      const bool up = (l15 & mm) != 0;
      #pragma unroll
      for (int k2 = 0; k2 < mm; ++k2){
        float sendA = up ? vA[k2] : vA[k2 + mm];
        float keepA = up ? vA[k2 + mm] : vA[k2];
        vA[k2] = keepA + __shfl_xor(sendA, mm, 64);
        float sendM = up ? vM[k2] : vM[k2 + mm];
        float keepM = up ? vM[k2 + mm] : vM[k2];
        vM[k2] = fmaxf(keepM, __shfl_xor(sendM, mm, 64));
      }
    }
    outb[4*it] = vA[0] + vM[0];
  }
}

extern "C" void kernel_launch(void* const* d_in, const int* in_sizes, int n_in,
                              void* d_out, int out_size, void* d_ws, size_t ws_size,
                              hipStream_t stream){
  (void)in_sizes; (void)n_in; (void)out_size; (void)ws_size;
  gsl_prep<<<dim3(1), dim3(512), 0, stream>>>(
    (const float*)d_in[7], (const float*)d_in[9], (const float*)d_in[10],
    (const float*)d_in[8], (float*)d_ws);
  gsl_fused<<<dim3(1024), dim3(256), 0, stream>>>(
    (const float*)d_in[0],  (const float*)d_in[1],  (const float*)d_in[2],
    (const float*)d_in[3],  (const float*)d_in[4],  (const float*)d_in[5],
    (const float*)d_in[6],  (const float*)d_in[7],  (const float*)d_in[8],
    (const float*)d_in[11], (const float*)d_in[12], (const float*)d_in[13],
    (const float*)d_in[14], (const float*)d_in[15], (const float*)d_in[16],
    (const float*)d_in[17], (const float*)d_in[18], (const float*)d_in[19],
    (const float*)d_in[20], (const float*)d_in[21], (const float*)d_in[22],
    (const float*)d_in[23], (const float*)d_in[24], (const float*)d_in[25],
    (const float*)d_in[26], (const float*)d_in[27], (const float*)d_in[28],
    (const float*)d_in[29], (const float*)d_ws, (float*)d_out);
}

// Round 15
// 71.023 us; speedup vs baseline: 3.7111x; 1.0707x over previous
//
#include <hip/hip_runtime.h>

// Grouped_Soft_GSL_Block_PE fused kernel for MI355X (gfx950).
// B=8, IC2=128, N=2048, K=32, C=64, G=8, CPG=8, hidden=16.
// R15: R11 structure (champion, 70.0us): 512 blocks (2/CU), 256 thr / 4
// waves, block owns 32 n, 8 iters of 4 n, wave wv owns n = nblk+4it+wv,
// zero barriers in loop, bank-optimal strides 132/68/36, butterfly
// epilogue, prep kernel for peW2/peBt. Single change vs R11: BOTH
// prefetch halves (fa AND fb) issue before the GEMM, giving all 16 HBM
// loads the full GEMM+pos+epilogue window to cover latency (R11 issued
// fb after the GEMM; its 8 loads only had the epilogue).

typedef __attribute__((ext_vector_type(8))) short bf16x8;
typedef __attribute__((ext_vector_type(4))) float f32x4;

#define EPS_BN 1e-5f

__device__ __forceinline__ unsigned pk2(float a, float b){
  unsigned ua = __float_as_uint(a) + 0x8000u;
  unsigned ub = __float_as_uint(b) + 0x8000u;
  return __builtin_amdgcn_perm(ub, ua, 0x07060302);
}
__device__ __forceinline__ short f2bf(float a){
  unsigned u = __float_as_uint(a);
  u += 0x7FFFu + ((u >> 16) & 1u);
  return (short)(u >> 16);
}
__device__ __forceinline__ float lrelu(float v){ return fmaxf(v, 0.2f*v); }

__device__ __forceinline__ void st8(short* dst, float4 a, float4 b){
  *(uint2*)(dst)     = make_uint2(pk2(a.x,a.y), pk2(a.z,a.w));
  *(uint2*)(dst + 4) = make_uint2(pk2(b.x,b.y), pk2(b.z,b.w));
}
__device__ __forceinline__ bf16x8 ld8(const short* p){
  union { bf16x8 v; uint2 q[2]; } w;
  w.q[0] = *(const uint2*)(p);
  w.q[1] = *(const uint2*)(p + 4);
  return w.v;
}

// DPP row_ror reductions over the 16-lane row (l15 = k dimension)
template<int N>
__device__ __forceinline__ float ror16(float x){
  return __int_as_float(__builtin_amdgcn_mov_dpp(__float_as_int(x), 0x120+N, 0xF, 0xF, false));
}
__device__ __forceinline__ float rsum16(float v){
  v += ror16<1>(v); v += ror16<2>(v); v += ror16<4>(v); v += ror16<8>(v); return v;
}
__device__ __forceinline__ float rmax16(float v){
  v = fmaxf(v, ror16<1>(v)); v = fmaxf(v, ror16<2>(v));
  v = fmaxf(v, ror16<4>(v)); v = fmaxf(v, ror16<8>(v)); return v;
}

#define MFMA16(a,b,c) __builtin_amdgcn_mfma_f32_16x16x32_bf16((a),(b),(c),0,0,0)

// prep: peW2 = pe_w @ pos_w2 (8x64, row-major) -> ws[0..511]; peBt -> ws[512..527]
__global__ void gsl_prep(const float* __restrict__ pos_w2, const float* __restrict__ pe_w,
                         const float* __restrict__ pe_b,   const float* __restrict__ pos_b2,
                         float* __restrict__ ws){
  int t = threadIdx.x;            // 0..511
  int r = t >> 6, j = t & 63;
  float s = 0.f;
  for (int c = 0; c < 64; ++c) s += pe_w[r*64 + c] * pos_w2[c*64 + j];
  ws[t] = s;
  if (t < 16){
    float v = 0.f;
    if (t < 8){
      v = pe_b[t];
      for (int c = 0; c < 64; ++c) v += pe_w[t*64 + c] * pos_b2[c];
    }
    ws[512 + t] = v;
  }
}

__global__ __launch_bounds__(256, 2)
void gsl_fused(const float* __restrict__ x,       const float* __restrict__ rel_pos,
               const float* __restrict__ pos_w1,  const float* __restrict__ pos_g,
               const float* __restrict__ pos_bb,  const float* __restrict__ pos_m,
               const float* __restrict__ pos_v,   const float* __restrict__ pos_w2,
               const float* __restrict__ pos_b2,  const float* __restrict__ trans_w,
               const float* __restrict__ tr_g,    const float* __restrict__ tr_bb,
               const float* __restrict__ tr_m,    const float* __restrict__ tr_v,
               const float* __restrict__ gate_w1, const float* __restrict__ ga_g,
               const float* __restrict__ ga_bb,   const float* __restrict__ ga_m,
               const float* __restrict__ ga_v,    const float* __restrict__ gate_w2,
               const float* __restrict__ gate_b2, const float* __restrict__ attn_w1,
               const float* __restrict__ at_g,    const float* __restrict__ at_bb,
               const float* __restrict__ at_m,    const float* __restrict__ at_v,
               const float* __restrict__ attn_w2, const float* __restrict__ attn_b2,
               const float* __restrict__ ws,      float* __restrict__ out)
{
  // LDS map (70784 B, 2 blocks/CU):
  // [0,33792)      xbuf [128 cols][132] bf16; wave slice 8448B at wv*8448,
  //                aliased post-GEMM per wave: h1b [32][68] @0, gab [32][36] @4352
  // [33792,59136)  wmain [96][132] bf16 (trans 0..63, gate 64..79, attn 80..95)
  // [59136,68928)  wpos2 [72][68] bf16 (rows 0..63 pos_w2; 64..71 peW2 from ws)
  // [68928,70784)  tabs f32: trQ[256] (s,b,pos_b2,0 quads) p1T[128] gaT[32] atT[32]
  __shared__ __align__(16) char smem[70784];
  short* xbuf  = (short*)smem;
  short* wmain = (short*)(smem + 33792);
  short* wpos2 = (short*)(smem + 59136);
  float* trQ  = (float*)(smem + 68928);
  float* p1T  = (float*)(smem + 69952);
  float* gaT  = (float*)(smem + 70464);
  float* atT  = (float*)(smem + 70592);

  const int tid = threadIdx.x;
  const int wv  = tid >> 6;
  const int l   = tid & 63;
  const int l15 = l & 15, g4 = l >> 4;
  const int bid = blockIdx.x;
  const int b    = bid >> 6;
  const int nblk = (bid & 63) << 5;

  // ---- stage weights -> LDS bf16 ----
  if (tid < 192){
    int r = tid >> 1, c0 = (tid & 1) * 64;
    const float* src = (r < 64) ? (trans_w + r*128)
                     : (r < 80) ? (gate_w1 + (r-64)*128)
                                : (attn_w1 + (r-80)*128);
    src += c0;
    short* dst = wmain + r*132 + c0;
    #pragma unroll
    for (int j = 0; j < 8; ++j)
      st8(dst + 8*j, *(const float4*)(src + 8*j), *(const float4*)(src + 8*j + 4));
  } else {
    int r = tid - 192;
    const float* src = pos_w2 + r*64;
    short* dst = wpos2 + r*68;
    #pragma unroll
    for (int j = 0; j < 8; ++j)
      st8(dst + 8*j, *(const float4*)(src + 8*j), *(const float4*)(src + 8*j + 4));
  }
  // peW2 rows 64..71 of wpos2 from ws
  if (tid < 16){
    int r = tid >> 1, c0 = (tid & 1) * 32;
    const float* src = ws + r*64 + c0;
    short* dst = wpos2 + (64 + r)*68 + c0;
    #pragma unroll
    for (int j = 0; j < 4; ++j)
      st8(dst + 8*j, *(const float4*)(src + 8*j), *(const float4*)(src + 8*j + 4));
  }
  // ---- BN fold tables ----
  if (tid < 64){
    float s = tr_g[tid] * rsqrtf(tr_v[tid] + EPS_BN);
    *(float4*)(trQ + 4*tid) = make_float4(s, tr_bb[tid] - tr_m[tid]*s, pos_b2[tid], 0.f);
    float s2 = pos_g[tid] * rsqrtf(pos_v[tid] + EPS_BN);
    p1T[2*tid] = s2; p1T[2*tid+1] = pos_bb[tid] - pos_m[tid]*s2;
  } else if (tid < 80){
    int c = tid - 64;
    float s = ga_g[c] * rsqrtf(ga_v[c] + EPS_BN);
    gaT[2*c] = s; gaT[2*c+1] = ga_bb[c] - ga_m[c]*s;
  } else if (tid < 96){
    int c = tid - 80;
    float s = at_g[c] * rsqrtf(at_v[c] + EPS_BN);
    atT[2*c] = s; atT[2*c+1] = at_bb[c] - at_m[c]*s;
  }

  // ---- small weights / consts -> registers ----
  uint2 pw1p[4];
  #pragma unroll
  for (int m2 = 0; m2 < 4; ++m2){
    uint2 t = make_uint2(0u, 0u);
    if (g4 == 0){
      const float* rp = pos_w1 + (16*m2 + l15)*3;
      t.x = pk2(rp[0], rp[1]);
      t.y = pk2(rp[2], 0.f);
    }
    pw1p[m2] = t;
  }
  bf16x8 gaf;
  {
    bf16x8 t = {0,0,0,0,0,0,0,0};
    #pragma unroll
    for (int j = 0; j < 8; ++j){
      int k = 8*g4 + j;
      float v2 = 0.f;
      if (l15 < 8)       { if (k >= 16) v2 = attn_w2[l15*16 + (k-16)]; }
      else if (l15 == 8) { if (k < 16)  v2 = gate_w2[k]; }
      t[j] = f2bf(v2);
    }
    gaf = t;
  }
  const float gb2v = gate_b2[0];
  float lcr[4];      // attn_b2 + peBt combined logit const
  #pragma unroll
  for (int r = 0; r < 4; ++r){
    int row = 4*g4 + r;
    lcr[r] = ws[512 + row] + ((row < 8) ? attn_b2[row] : 0.f);
  }

  // ---- per-wave constants ----
  const int col0 = 32*wv + l15, col1 = col0 + 16;
  const int lc0 = l15, lc1 = l15 + 16;
  const int lq = l & 7, ld = l >> 3;
  const int colb = 32*wv + 4*lq;
  char*  slice = smem + wv*8448;
  short* h1b   = (short*)slice;            // [32][68]
  short* gab   = (short*)(slice + 4352);   // [32][36]
  const float* xp0 = x + (((long)(b*128 + 8*ld)) << 16) + colb;
  const float* rpb = rel_pos + (((long)(3*b)) << 16);
  const int och = 16*(l15 >> 2) + 4*g4 + (l15 & 3);   // butterfly output channel
  float* outb = out + (((long)(b*64 + och)) << 11) + nblk + wv;

  // ---- prologue: prefetch iteration 0 ----
  f32x4 fa[8], fb[8];
  float rc[6] = {0.f,0.f,0.f,0.f,0.f,0.f};
  {
    const long sb0 = (long)nblk * 32;
    #pragma unroll
    for (int j = 0; j < 8; ++j) fa[j] = *(const f32x4*)(xp0 + sb0 + (((long)j) << 16));
    #pragma unroll
    for (int j = 0; j < 8; ++j) fb[j] = *(const f32x4*)(xp0 + sb0 + (((long)(64+j)) << 16));
    if (g4 == 0){
      long sg = sb0 + col0;
      rc[0] = rpb[sg];          rc[1] = rpb[sg + 65536];      rc[2] = rpb[sg + 131072];
      rc[3] = rpb[sg + 16];     rc[4] = rpb[sg + 65536 + 16]; rc[5] = rpb[sg + 131072 + 16];
    }
  }

  __syncthreads();   // LDS weights + tables visible

  for (int it = 0; it < 8; ++it){
    const long sbase = (long)nblk*32 + 128*it;

    // (1) cvt + write staged tile -> own xbuf slice (consumes fa,fb)
    #pragma unroll
    for (int i2 = 0; i2 < 4; ++i2){
      short* dst = xbuf + (colb+i2)*132 + 8*ld;
      *(uint2*)(dst)      = make_uint2(pk2(fa[0][i2],fa[1][i2]), pk2(fa[2][i2],fa[3][i2]));
      *(uint2*)(dst + 4)  = make_uint2(pk2(fa[4][i2],fa[5][i2]), pk2(fa[6][i2],fa[7][i2]));
      *(uint2*)(dst + 64) = make_uint2(pk2(fb[0][i2],fb[1][i2]), pk2(fb[2][i2],fb[3][i2]));
      *(uint2*)(dst + 68) = make_uint2(pk2(fb[4][i2],fb[5][i2]), pk2(fb[6][i2],fb[7][i2]));
    }

    const long nsb = sbase + 128;
    // (2) prefetch BOTH halves for next iter (full iteration to cover latency)
    if (it < 7){
      #pragma unroll
      for (int j = 0; j < 8; ++j) fa[j] = *(const f32x4*)(xp0 + nsb + (((long)j) << 16));
      #pragma unroll
      for (int j = 0; j < 8; ++j) fb[j] = *(const f32x4*)(xp0 + nsb + (((long)(64+j)) << 16));
    }

    // (3) main GEMM: [96x128] @ xtile
    f32x4 acc[6][2];
    #pragma unroll
    for (int m = 0; m < 6; ++m){
      f32x4 z = {0.f,0.f,0.f,0.f};
      acc[m][0] = z; acc[m][1] = z;
    }
    #pragma unroll
    for (int ks = 0; ks < 4; ++ks){
      bf16x8 b0 = ld8(xbuf + col0*132 + 32*ks + 8*g4);
      bf16x8 b1 = ld8(xbuf + col1*132 + 32*ks + 8*g4);
      #pragma unroll
      for (int m = 0; m < 6; ++m){
        bf16x8 af = ld8(wmain + (16*m + l15)*132 + 32*ks + 8*g4);
        acc[m][0] = MFMA16(af, b0, acc[m][0]);
        acc[m][1] = MFMA16(af, b1, acc[m][1]);
      }
    }

    // (4) pos layer 1 (K padded 3->32) -> h1b ; uses rc of CURRENT iter
    {
      bf16x8 rf0 = {0,0,0,0,0,0,0,0}, rf1 = {0,0,0,0,0,0,0,0};
      if (g4 == 0){
        union { bf16x8 v; unsigned u[4]; } t0, t1;
        t0.u[0] = pk2(rc[0], rc[1]); t0.u[1] = pk2(rc[2], 0.f); t0.u[2] = 0u; t0.u[3] = 0u;
        t1.u[0] = pk2(rc[3], rc[4]); t1.u[1] = pk2(rc[5], 0.f); t1.u[2] = 0u; t1.u[3] = 0u;
        rf0 = t0.v; rf1 = t1.v;
      }
      #pragma unroll
      for (int m2 = 0; m2 < 4; ++m2){
        union { bf16x8 v; unsigned u[4]; } aw;
        aw.u[0] = pw1p[m2].x; aw.u[1] = pw1p[m2].y; aw.u[2] = 0u; aw.u[3] = 0u;
        f32x4 z = {0.f,0.f,0.f,0.f};
        f32x4 d0 = MFMA16(aw.v, rf0, z);
        f32x4 d1 = MFMA16(aw.v, rf1, z);
        int cb2 = 16*m2 + 4*g4;
        float2 t0 = *(const float2*)(p1T + 2*(cb2+0));
        float2 t1 = *(const float2*)(p1T + 2*(cb2+1));
        float2 t2 = *(const float2*)(p1T + 2*(cb2+2));
        float2 t3 = *(const float2*)(p1T + 2*(cb2+3));
        float h0 = lrelu(t0.x*d0[0]+t0.y), h1v = lrelu(t1.x*d0[1]+t1.y);
        float h2 = lrelu(t2.x*d0[2]+t2.y), h3 = lrelu(t3.x*d0[3]+t3.y);
        *(uint2*)(h1b + lc0*68 + cb2) = make_uint2(pk2(h0,h1v), pk2(h2,h3));
        h0 = lrelu(t0.x*d1[0]+t0.y); h1v = lrelu(t1.x*d1[1]+t1.y);
        h2 = lrelu(t2.x*d1[2]+t2.y); h3 = lrelu(t3.x*d1[3]+t3.y);
        *(uint2*)(h1b + lc1*68 + cb2) = make_uint2(pk2(h0,h1v), pk2(h2,h3));
      }
    }
    // (4b) prefetch rel_pos for NEXT iter (after use)
    if (g4 == 0 && it < 7){
      long sg = nsb + col0;
      rc[0] = rpb[sg];          rc[1] = rpb[sg + 65536];      rc[2] = rpb[sg + 131072];
      rc[3] = rpb[sg + 16];     rc[4] = rpb[sg + 65536 + 16]; rc[5] = rpb[sg + 131072 + 16];
    }

    // (5) trans epilogue FIRST: acc[0..3] = lrelu(BN(conv)) + pos_b2
    #pragma unroll
    for (int m = 0; m < 4; ++m)
      #pragma unroll
      for (int r = 0; r < 4; ++r){
        float4 tq = *(const float4*)(trQ + 4*(16*m + 4*g4 + r));
        acc[m][0][r] = lrelu(tq.x*acc[m][0][r] + tq.y) + tq.z;
        acc[m][1][r] = lrelu(tq.x*acc[m][1][r] + tq.y) + tq.z;
      }

    // (6) pos2 MFMAs accumulate INTO acc[0..3]; pe-fold rows -> pac4
    f32x4 pac4[2];
    {
      f32x4 z = {0.f,0.f,0.f,0.f};
      pac4[0] = z; pac4[1] = z;
    }
    #pragma unroll
    for (int ks = 0; ks < 2; ++ks){
      bf16x8 h0 = ld8(h1b + lc0*68 + 32*ks + 8*g4);
      bf16x8 h1v = ld8(h1b + lc1*68 + 32*ks + 8*g4);
      #pragma unroll
      for (int m2 = 0; m2 < 4; ++m2){
        bf16x8 af = ld8(wpos2 + (16*m2 + l15)*68 + 32*ks + 8*g4);
        acc[m2][0] = MFMA16(af, h0, acc[m2][0]);
        acc[m2][1] = MFMA16(af, h1v, acc[m2][1]);
      }
      bf16x8 af4 = ld8(wpos2 + (64 + l15)*68 + 32*ks + 8*g4);
      pac4[0] = MFMA16(af4, h0, pac4[0]);
      pac4[1] = MFMA16(af4, h1v, pac4[1]);
    }

    // (7) hidden epilogues -> gab (gate_h ch 0..15, attn_h ch 16..31)
    {
      int hc = 4*g4;
      float2 g0p = *(const float2*)(gaT + 2*(hc+0));
      float2 g1p = *(const float2*)(gaT + 2*(hc+1));
      float2 g2p = *(const float2*)(gaT + 2*(hc+2));
      float2 g3p = *(const float2*)(gaT + 2*(hc+3));
      float2 a0p = *(const float2*)(atT + 2*(hc+0));
      float2 a1p = *(const float2*)(atT + 2*(hc+1));
      float2 a2p = *(const float2*)(atT + 2*(hc+2));
      float2 a3p = *(const float2*)(atT + 2*(hc+3));
      #pragma unroll
      for (int ct = 0; ct < 2; ++ct){
        int lc = (ct == 0) ? lc0 : lc1;
        float q0 = lrelu(g0p.x*acc[4][ct][0] + g0p.y), q1 = lrelu(g1p.x*acc[4][ct][1] + g1p.y);
        float q2 = lrelu(g2p.x*acc[4][ct][2] + g2p.y), q3 = lrelu(g3p.x*acc[4][ct][3] + g3p.y);
        *(uint2*)(gab + lc*36 + hc) = make_uint2(pk2(q0,q1), pk2(q2,q3));
        float a0 = lrelu(a0p.x*acc[5][ct][0] + a0p.y), a1 = lrelu(a1p.x*acc[5][ct][1] + a1p.y);
        float a2 = lrelu(a2p.x*acc[5][ct][2] + a2p.y), a3 = lrelu(a3p.x*acc[5][ct][3] + a3p.y);
        *(uint2*)(gab + lc*36 + 16 + hc) = make_uint2(pk2(a0,a1), pk2(a2,a3));
      }
    }

    // (8) gate/attn layer-2 MFMA (rows 0..7 attn, row 8 gate)
    f32x4 gac0 = {0.f,0.f,0.f,0.f}, gac1 = gac0;
    {
      bf16x8 g0 = ld8(gab + lc0*36 + 8*g4);
      bf16x8 g1 = ld8(gab + lc1*36 + 8*g4);
      gac0 = MFMA16(gaf, g0, gac0);
      gac1 = MFMA16(gaf, g1, gac1);
    }

    // (9) gate + logits + softmax over k (DPP reduce)
    float gv0 = __shfl(gac0[0], 32 + l15, 64);
    float gv1 = __shfl(gac1[0], 32 + l15, 64);
    float gm0 = 1.f/(1.f + __expf(-(gv0 + gb2v)));
    float gm1 = 1.f/(1.f + __expf(-(gv1 + gb2v)));
    float lg0 = __logf(gm0 + 1e-6f), lg1 = __logf(gm1 + 1e-6f);

    float wg0[4], wg1[4];
    #pragma unroll
    for (int r = 0; r < 4; ++r){
      float t0 = gac0[r] + pac4[0][r] + lcr[r] + lg0;
      float t1 = gac1[r] + pac4[1][r] + lcr[r] + lg1;
      float mx = rmax16(fmaxf(t0, t1));
      float e0 = __expf(t0 - mx), e1 = __expf(t1 - mx);
      float inv = 1.f / rsum16(e0 + e1);
      wg0[r] = e0 * inv; wg1[r] = e1 * inv;
    }

    // (10) fill vA/vM then reduce-scatter butterfly; one 64-lane store
    float vA[16], vM[16];
    const bool hi = (g4 >= 2);
    #pragma unroll
    for (int m = 0; m < 4; ++m){
      int src = 16*(m >> 1) + l15;
      float a0 = __shfl(wg0[(2*m) & 3],   src, 64);
      float b0 = __shfl(wg0[(2*m+1) & 3], src, 64);
      float a1 = __shfl(wg1[(2*m) & 3],   src, 64);
      float b1 = __shfl(wg1[(2*m+1) & 3], src, 64);
      float w0 = hi ? b0 : a0;
      float w1 = hi ? b1 : a1;
      #pragma unroll
      for (int r = 0; r < 4; ++r){
        vA[4*m+r] = acc[m][0][r]*w0 + acc[m][1][r]*w1;
        vM[4*m+r] = fmaxf(acc[m][0][r]*gm0, acc[m][1][r]*gm1);
      }
    }
    #pragma unroll
    for (int s = 0; s < 4; ++s){
      const int mm = 8 >> s;
      const bool up = (l15 & mm) != 0;
      #pragma unroll
      for (int k2 = 0; k2 < mm; ++k2){
        float sendA = up ? vA[k2] : vA[k2 + mm];
        float keepA = up ? vA[k2 + mm] : vA[k2];
        vA[k2] = keepA + __shfl_xor(sendA, mm, 64);
        float sendM = up ? vM[k2] : vM[k2 + mm];
        float keepM = up ? vM[k2 + mm] : vM[k2];
        vM[k2] = fmaxf(keepM, __shfl_xor(sendM, mm, 64));
      }
    }
    outb[4*it] = vA[0] + vM[0];
  }
}

extern "C" void kernel_launch(void* const* d_in, const int* in_sizes, int n_in,
                              void* d_out, int out_size, void* d_ws, size_t ws_size,
                              hipStream_t stream){
  (void)in_sizes; (void)n_in; (void)out_size; (void)ws_size;
  gsl_prep<<<dim3(1), dim3(512), 0, stream>>>(
    (const float*)d_in[7], (const float*)d_in[9], (const float*)d_in[10],
    (const float*)d_in[8], (float*)d_ws);
  gsl_fused<<<dim3(512), dim3(256), 0, stream>>>(
    (const float*)d_in[0],  (const float*)d_in[1],  (const float*)d_in[2],
    (const float*)d_in[3],  (const float*)d_in[4],  (const float*)d_in[5],
    (const float*)d_in[6],  (const float*)d_in[7],  (const float*)d_in[8],
    (const float*)d_in[11], (const float*)d_in[12], (const float*)d_in[13],
    (const float*)d_in[14], (const float*)d_in[15], (const float*)d_in[16],
    (const float*)d_in[17], (const float*)d_in[18], (const float*)d_in[19],
    (const float*)d_in[20], (const float*)d_in[21], (const float*)d_in[22],
    (const float*)d_in[23], (const float*)d_in[24], (const float*)d_in[25],
    (const float*)d_in[26], (const float*)d_in[27], (const float*)d_in[28],
    (const float*)d_in[29], (const float*)d_ws, (float*)d_out);
}

// Round 16
// 70.002 us; speedup vs baseline: 3.7653x; 1.0146x over previous
//
#include <hip/hip_runtime.h>

// Grouped_Soft_GSL_Block_PE fused kernel for MI355X (gfx950).
// B=8, IC2=128, N=2048, K=32, C=64, G=8, CPG=8, hidden=16.
// R16 = R11 (session champion, 70.0us): 512 blocks (2/CU), 256 thr / 4
// waves; block owns 32 n, 8 iterations of 4 n; wave wv owns n = nblk+4it+wv.
// Zero barriers in loop; bank-optimal LDS strides 132/68/36; reduce-scatter
// butterfly epilogue (distributed result -> one 64-lane store); peW2/peBt
// folds precomputed by prep kernel into d_ws.
// Structural notes (measured over R0-R15):
//  - 2 waves/SIMD is a hard cap: unified VGPR+AGPR file; (256,3) splits
//    ~84 arch VGPRs and the 64-reg f32 prefetch then spills (R6/R8/R12/R13).
//  - Bank conflicts, grid backfill, prefetch issue order: all neutral here
//    (latency-bound regime; R10/R14/R15).

typedef __attribute__((ext_vector_type(8))) short bf16x8;
typedef __attribute__((ext_vector_type(4))) float f32x4;

#define EPS_BN 1e-5f

__device__ __forceinline__ unsigned pk2(float a, float b){
  unsigned ua = __float_as_uint(a) + 0x8000u;
  unsigned ub = __float_as_uint(b) + 0x8000u;
  return __builtin_amdgcn_perm(ub, ua, 0x07060302);
}
__device__ __forceinline__ short f2bf(float a){
  unsigned u = __float_as_uint(a);
  u += 0x7FFFu + ((u >> 16) & 1u);
  return (short)(u >> 16);
}
__device__ __forceinline__ float lrelu(float v){ return fmaxf(v, 0.2f*v); }

__device__ __forceinline__ void st8(short* dst, float4 a, float4 b){
  *(uint2*)(dst)     = make_uint2(pk2(a.x,a.y), pk2(a.z,a.w));
  *(uint2*)(dst + 4) = make_uint2(pk2(b.x,b.y), pk2(b.z,b.w));
}
__device__ __forceinline__ bf16x8 ld8(const short* p){
  union { bf16x8 v; uint2 q[2]; } w;
  w.q[0] = *(const uint2*)(p);
  w.q[1] = *(const uint2*)(p + 4);
  return w.v;
}

// DPP row_ror reductions over the 16-lane row (l15 = k dimension)
template<int N>
__device__ __forceinline__ float ror16(float x){
  return __int_as_float(__builtin_amdgcn_mov_dpp(__float_as_int(x), 0x120+N, 0xF, 0xF, false));
}
__device__ __forceinline__ float rsum16(float v){
  v += ror16<1>(v); v += ror16<2>(v); v += ror16<4>(v); v += ror16<8>(v); return v;
}
__device__ __forceinline__ float rmax16(float v){
  v = fmaxf(v, ror16<1>(v)); v = fmaxf(v, ror16<2>(v));
  v = fmaxf(v, ror16<4>(v)); v = fmaxf(v, ror16<8>(v)); return v;
}

#define MFMA16(a,b,c) __builtin_amdgcn_mfma_f32_16x16x32_bf16((a),(b),(c),0,0,0)

// prep: peW2 = pe_w @ pos_w2 (8x64, row-major) -> ws[0..511]; peBt -> ws[512..527]
__global__ void gsl_prep(const float* __restrict__ pos_w2, const float* __restrict__ pe_w,
                         const float* __restrict__ pe_b,   const float* __restrict__ pos_b2,
                         float* __restrict__ ws){
  int t = threadIdx.x;            // 0..511
  int r = t >> 6, j = t & 63;
  float s = 0.f;
  for (int c = 0; c < 64; ++c) s += pe_w[r*64 + c] * pos_w2[c*64 + j];
  ws[t] = s;
  if (t < 16){
    float v = 0.f;
    if (t < 8){
      v = pe_b[t];
      for (int c = 0; c < 64; ++c) v += pe_w[t*64 + c] * pos_b2[c];
    }
    ws[512 + t] = v;
  }
}

__global__ __launch_bounds__(256, 2)
void gsl_fused(const float* __restrict__ x,       const float* __restrict__ rel_pos,
               const float* __restrict__ pos_w1,  const float* __restrict__ pos_g,
               const float* __restrict__ pos_bb,  const float* __restrict__ pos_m,
               const float* __restrict__ pos_v,   const float* __restrict__ pos_w2,
               const float* __restrict__ pos_b2,  const float* __restrict__ trans_w,
               const float* __restrict__ tr_g,    const float* __restrict__ tr_bb,
               const float* __restrict__ tr_m,    const float* __restrict__ tr_v,
               const float* __restrict__ gate_w1, const float* __restrict__ ga_g,
               const float* __restrict__ ga_bb,   const float* __restrict__ ga_m,
               const float* __restrict__ ga_v,    const float* __restrict__ gate_w2,
               const float* __restrict__ gate_b2, const float* __restrict__ attn_w1,
               const float* __restrict__ at_g,    const float* __restrict__ at_bb,
               const float* __restrict__ at_m,    const float* __restrict__ at_v,
               const float* __restrict__ attn_w2, const float* __restrict__ attn_b2,
               const float* __restrict__ ws,      float* __restrict__ out)
{
  // LDS map (70784 B, 2 blocks/CU):
  // [0,33792)      xbuf [128 cols][132] bf16; wave slice 8448B at wv*8448,
  //                aliased post-GEMM per wave: h1b [32][68] @0, gab [32][36] @4352
  // [33792,59136)  wmain [96][132] bf16 (trans 0..63, gate 64..79, attn 80..95)
  // [59136,68928)  wpos2 [72][68] bf16 (rows 0..63 pos_w2; 64..71 peW2 from ws)
  // [68928,70784)  tabs f32: trQ[256] (s,b,pos_b2,0 quads) p1T[128] gaT[32] atT[32]
  __shared__ __align__(16) char smem[70784];
  short* xbuf  = (short*)smem;
  short* wmain = (short*)(smem + 33792);
  short* wpos2 = (short*)(smem + 59136);
  float* trQ  = (float*)(smem + 68928);
  float* p1T  = (float*)(smem + 69952);
  float* gaT  = (float*)(smem + 70464);
  float* atT  = (float*)(smem + 70592);

  const int tid = threadIdx.x;
  const int wv  = tid >> 6;
  const int l   = tid & 63;
  const int l15 = l & 15, g4 = l >> 4;
  const int bid = blockIdx.x;
  const int b    = bid >> 6;
  const int nblk = (bid & 63) << 5;

  // ---- stage weights -> LDS bf16 ----
  if (tid < 192){
    int r = tid >> 1, c0 = (tid & 1) * 64;
    const float* src = (r < 64) ? (trans_w + r*128)
                     : (r < 80) ? (gate_w1 + (r-64)*128)
                                : (attn_w1 + (r-80)*128);
    src += c0;
    short* dst = wmain + r*132 + c0;
    #pragma unroll
    for (int j = 0; j < 8; ++j)
      st8(dst + 8*j, *(const float4*)(src + 8*j), *(const float4*)(src + 8*j + 4));
  } else {
    int r = tid - 192;
    const float* src = pos_w2 + r*64;
    short* dst = wpos2 + r*68;
    #pragma unroll
    for (int j = 0; j < 8; ++j)
      st8(dst + 8*j, *(const float4*)(src + 8*j), *(const float4*)(src + 8*j + 4));
  }
  // peW2 rows 64..71 of wpos2 from ws
  if (tid < 16){
    int r = tid >> 1, c0 = (tid & 1) * 32;
    const float* src = ws + r*64 + c0;
    short* dst = wpos2 + (64 + r)*68 + c0;
    #pragma unroll
    for (int j = 0; j < 4; ++j)
      st8(dst + 8*j, *(const float4*)(src + 8*j), *(const float4*)(src + 8*j + 4));
  }
  // ---- BN fold tables ----
  if (tid < 64){
    float s = tr_g[tid] * rsqrtf(tr_v[tid] + EPS_BN);
    *(float4*)(trQ + 4*tid) = make_float4(s, tr_bb[tid] - tr_m[tid]*s, pos_b2[tid], 0.f);
    float s2 = pos_g[tid] * rsqrtf(pos_v[tid] + EPS_BN);
    p1T[2*tid] = s2; p1T[2*tid+1] = pos_bb[tid] - pos_m[tid]*s2;
  } else if (tid < 80){
    int c = tid - 64;
    float s = ga_g[c] * rsqrtf(ga_v[c] + EPS_BN);
    gaT[2*c] = s; gaT[2*c+1] = ga_bb[c] - ga_m[c]*s;
  } else if (tid < 96){
    int c = tid - 80;
    float s = at_g[c] * rsqrtf(at_v[c] + EPS_BN);
    atT[2*c] = s; atT[2*c+1] = at_bb[c] - at_m[c]*s;
  }

  // ---- small weights / consts -> registers ----
  uint2 pw1p[4];
  #pragma unroll
  for (int m2 = 0; m2 < 4; ++m2){
    uint2 t = make_uint2(0u, 0u);
    if (g4 == 0){
      const float* rp = pos_w1 + (16*m2 + l15)*3;
      t.x = pk2(rp[0], rp[1]);
      t.y = pk2(rp[2], 0.f);
    }
    pw1p[m2] = t;
  }
  bf16x8 gaf;
  {
    bf16x8 t = {0,0,0,0,0,0,0,0};
    #pragma unroll
    for (int j = 0; j < 8; ++j){
      int k = 8*g4 + j;
      float v2 = 0.f;
      if (l15 < 8)       { if (k >= 16) v2 = attn_w2[l15*16 + (k-16)]; }
      else if (l15 == 8) { if (k < 16)  v2 = gate_w2[k]; }
      t[j] = f2bf(v2);
    }
    gaf = t;
  }
  const float gb2v = gate_b2[0];
  float lcr[4];      // attn_b2 + peBt combined logit const
  #pragma unroll
  for (int r = 0; r < 4; ++r){
    int row = 4*g4 + r;
    lcr[r] = ws[512 + row] + ((row < 8) ? attn_b2[row] : 0.f);
  }

  // ---- per-wave constants ----
  const int col0 = 32*wv + l15, col1 = col0 + 16;
  const int lc0 = l15, lc1 = l15 + 16;
  const int lq = l & 7, ld = l >> 3;
  const int colb = 32*wv + 4*lq;
  char*  slice = smem + wv*8448;
  short* h1b   = (short*)slice;            // [32][68]
  short* gab   = (short*)(slice + 4352);   // [32][36]
  const float* xp0 = x + (((long)(b*128 + 8*ld)) << 16) + colb;
  const float* rpb = rel_pos + (((long)(3*b)) << 16);
  const int och = 16*(l15 >> 2) + 4*g4 + (l15 & 3);   // butterfly output channel
  float* outb = out + (((long)(b*64 + och)) << 11) + nblk + wv;

  // ---- prologue: prefetch iteration 0 ----
  f32x4 fa[8], fb[8];
  float rc[6] = {0.f,0.f,0.f,0.f,0.f,0.f};
  {
    const long sb0 = (long)nblk * 32;
    #pragma unroll
    for (int j = 0; j < 8; ++j) fa[j] = *(const f32x4*)(xp0 + sb0 + (((long)j) << 16));
    #pragma unroll
    for (int j = 0; j < 8; ++j) fb[j] = *(const f32x4*)(xp0 + sb0 + (((long)(64+j)) << 16));
    if (g4 == 0){
      long sg = sb0 + col0;
      rc[0] = rpb[sg];          rc[1] = rpb[sg + 65536];      rc[2] = rpb[sg + 131072];
      rc[3] = rpb[sg + 16];     rc[4] = rpb[sg + 65536 + 16]; rc[5] = rpb[sg + 131072 + 16];
    }
  }

  __syncthreads();   // LDS weights + tables visible

  for (int it = 0; it < 8; ++it){
    const long sbase = (long)nblk*32 + 128*it;

    // (1) cvt + write staged tile -> own xbuf slice (consumes fa,fb)
    #pragma unroll
    for (int i2 = 0; i2 < 4; ++i2){
      short* dst = xbuf + (colb+i2)*132 + 8*ld;
      *(uint2*)(dst)      = make_uint2(pk2(fa[0][i2],fa[1][i2]), pk2(fa[2][i2],fa[3][i2]));
      *(uint2*)(dst + 4)  = make_uint2(pk2(fa[4][i2],fa[5][i2]), pk2(fa[6][i2],fa[7][i2]));
      *(uint2*)(dst + 64) = make_uint2(pk2(fb[0][i2],fb[1][i2]), pk2(fb[2][i2],fb[3][i2]));
      *(uint2*)(dst + 68) = make_uint2(pk2(fb[4][i2],fb[5][i2]), pk2(fb[6][i2],fb[7][i2]));
    }

    const long nsb = sbase + 128;
    // (2) prefetch fa half for next iter (in flight across GEMM)
    if (it < 7){
      #pragma unroll
      for (int j = 0; j < 8; ++j) fa[j] = *(const f32x4*)(xp0 + nsb + (((long)j) << 16));
    }

    // (3) main GEMM: [96x128] @ xtile
    f32x4 acc[6][2];
    #pragma unroll
    for (int m = 0; m < 6; ++m){
      f32x4 z = {0.f,0.f,0.f,0.f};
      acc[m][0] = z; acc[m][1] = z;
    }
    #pragma unroll
    for (int ks = 0; ks < 4; ++ks){
      bf16x8 b0 = ld8(xbuf + col0*132 + 32*ks + 8*g4);
      bf16x8 b1 = ld8(xbuf + col1*132 + 32*ks + 8*g4);
      #pragma unroll
      for (int m = 0; m < 6; ++m){
        bf16x8 af = ld8(wmain + (16*m + l15)*132 + 32*ks + 8*g4);
        acc[m][0] = MFMA16(af, b0, acc[m][0]);
        acc[m][1] = MFMA16(af, b1, acc[m][1]);
      }
    }

    // (4) prefetch fb half for next iter (in flight across epilogue)
    if (it < 7){
      #pragma unroll
      for (int j = 0; j < 8; ++j) fb[j] = *(const f32x4*)(xp0 + nsb + (((long)(64+j)) << 16));
    }

    // (5) pos layer 1 (K padded 3->32) -> h1b ; uses rc of CURRENT iter
    {
      bf16x8 rf0 = {0,0,0,0,0,0,0,0}, rf1 = {0,0,0,0,0,0,0,0};
      if (g4 == 0){
        union { bf16x8 v; unsigned u[4]; } t0, t1;
        t0.u[0] = pk2(rc[0], rc[1]); t0.u[1] = pk2(rc[2], 0.f); t0.u[2] = 0u; t0.u[3] = 0u;
        t1.u[0] = pk2(rc[3], rc[4]); t1.u[1] = pk2(rc[5], 0.f); t1.u[2] = 0u; t1.u[3] = 0u;
        rf0 = t0.v; rf1 = t1.v;
      }
      #pragma unroll
      for (int m2 = 0; m2 < 4; ++m2){
        union { bf16x8 v; unsigned u[4]; } aw;
        aw.u[0] = pw1p[m2].x; aw.u[1] = pw1p[m2].y; aw.u[2] = 0u; aw.u[3] = 0u;
        f32x4 z = {0.f,0.f,0.f,0.f};
        f32x4 d0 = MFMA16(aw.v, rf0, z);
        f32x4 d1 = MFMA16(aw.v, rf1, z);
        int cb2 = 16*m2 + 4*g4;
        float2 t0 = *(const float2*)(p1T + 2*(cb2+0));
        float2 t1 = *(const float2*)(p1T + 2*(cb2+1));
        float2 t2 = *(const float2*)(p1T + 2*(cb2+2));
        float2 t3 = *(const float2*)(p1T + 2*(cb2+3));
        float h0 = lrelu(t0.x*d0[0]+t0.y), h1v = lrelu(t1.x*d0[1]+t1.y);
        float h2 = lrelu(t2.x*d0[2]+t2.y), h3 = lrelu(t3.x*d0[3]+t3.y);
        *(uint2*)(h1b + lc0*68 + cb2) = make_uint2(pk2(h0,h1v), pk2(h2,h3));
        h0 = lrelu(t0.x*d1[0]+t0.y); h1v = lrelu(t1.x*d1[1]+t1.y);
        h2 = lrelu(t2.x*d1[2]+t2.y); h3 = lrelu(t3.x*d1[3]+t3.y);
        *(uint2*)(h1b + lc1*68 + cb2) = make_uint2(pk2(h0,h1v), pk2(h2,h3));
      }
    }
    // (5b) prefetch rel_pos for NEXT iter (after use)
    if (g4 == 0 && it < 7){
      long sg = nsb + col0;
      rc[0] = rpb[sg];          rc[1] = rpb[sg + 65536];      rc[2] = rpb[sg + 131072];
      rc[3] = rpb[sg + 16];     rc[4] = rpb[sg + 65536 + 16]; rc[5] = rpb[sg + 131072 + 16];
    }

    // (6) trans epilogue FIRST: acc[0..3] = lrelu(BN(conv)) + pos_b2
    #pragma unroll
    for (int m = 0; m < 4; ++m)
      #pragma unroll
      for (int r = 0; r < 4; ++r){
        float4 tq = *(const float4*)(trQ + 4*(16*m + 4*g4 + r));
        acc[m][0][r] = lrelu(tq.x*acc[m][0][r] + tq.y) + tq.z;
        acc[m][1][r] = lrelu(tq.x*acc[m][1][r] + tq.y) + tq.z;
      }

    // (7) pos2 MFMAs accumulate INTO acc[0..3]; pe-fold rows -> pac4
    f32x4 pac4[2];
    {
      f32x4 z = {0.f,0.f,0.f,0.f};
      pac4[0] = z; pac4[1] = z;
    }
    #pragma unroll
    for (int ks = 0; ks < 2; ++ks){
      bf16x8 h0 = ld8(h1b + lc0*68 + 32*ks + 8*g4);
      bf16x8 h1v = ld8(h1b + lc1*68 + 32*ks + 8*g4);
      #pragma unroll
      for (int m2 = 0; m2 < 4; ++m2){
        bf16x8 af = ld8(wpos2 + (16*m2 + l15)*68 + 32*ks + 8*g4);
        acc[m2][0] = MFMA16(af, h0, acc[m2][0]);
        acc[m2][1] = MFMA16(af, h1v, acc[m2][1]);
      }
      bf16x8 af4 = ld8(wpos2 + (64 + l15)*68 + 32*ks + 8*g4);
      pac4[0] = MFMA16(af4, h0, pac4[0]);
      pac4[1] = MFMA16(af4, h1v, pac4[1]);
    }

    // (8) hidden epilogues -> gab (gate_h ch 0..15, attn_h ch 16..31)
    {
      int hc = 4*g4;
      float2 g0p = *(const float2*)(gaT + 2*(hc+0));
      float2 g1p = *(const float2*)(gaT + 2*(hc+1));
      float2 g2p = *(const float2*)(gaT + 2*(hc+2));
      float2 g3p = *(const float2*)(gaT + 2*(hc+3));
      float2 a0p = *(const float2*)(atT + 2*(hc+0));
      float2 a1p = *(const float2*)(atT + 2*(hc+1));
      float2 a2p = *(const float2*)(atT + 2*(hc+2));
      float2 a3p = *(const float2*)(atT + 2*(hc+3));
      #pragma unroll
      for (int ct = 0; ct < 2; ++ct){
        int lc = (ct == 0) ? lc0 : lc1;
        float q0 = lrelu(g0p.x*acc[4][ct][0] + g0p.y), q1 = lrelu(g1p.x*acc[4][ct][1] + g1p.y);
        float q2 = lrelu(g2p.x*acc[4][ct][2] + g2p.y), q3 = lrelu(g3p.x*acc[4][ct][3] + g3p.y);
        *(uint2*)(gab + lc*36 + hc) = make_uint2(pk2(q0,q1), pk2(q2,q3));
        float a0 = lrelu(a0p.x*acc[5][ct][0] + a0p.y), a1 = lrelu(a1p.x*acc[5][ct][1] + a1p.y);
        float a2 = lrelu(a2p.x*acc[5][ct][2] + a2p.y), a3 = lrelu(a3p.x*acc[5][ct][3] + a3p.y);
        *(uint2*)(gab + lc*36 + 16 + hc) = make_uint2(pk2(a0,a1), pk2(a2,a3));
      }
    }

    // (9) gate/attn layer-2 MFMA (rows 0..7 attn, row 8 gate)
    f32x4 gac0 = {0.f,0.f,0.f,0.f}, gac1 = gac0;
    {
      bf16x8 g0 = ld8(gab + lc0*36 + 8*g4);
      bf16x8 g1 = ld8(gab + lc1*36 + 8*g4);
      gac0 = MFMA16(gaf, g0, gac0);
      gac1 = MFMA16(gaf, g1, gac1);
    }

    // (10) gate + logits + softmax over k (DPP reduce)
    float gv0 = __shfl(gac0[0], 32 + l15, 64);
    float gv1 = __shfl(gac1[0], 32 + l15, 64);
    float gm0 = 1.f/(1.f + __expf(-(gv0 + gb2v)));
    float gm1 = 1.f/(1.f + __expf(-(gv1 + gb2v)));
    float lg0 = __logf(gm0 + 1e-6f), lg1 = __logf(gm1 + 1e-6f);

    float wg0[4], wg1[4];
    #pragma unroll
    for (int r = 0; r < 4; ++r){
      float t0 = gac0[r] + pac4[0][r] + lcr[r] + lg0;
      float t1 = gac1[r] + pac4[1][r] + lcr[r] + lg1;
      float mx = rmax16(fmaxf(t0, t1));
      float e0 = __expf(t0 - mx), e1 = __expf(t1 - mx);
      float inv = 1.f / rsum16(e0 + e1);
      wg0[r] = e0 * inv; wg1[r] = e1 * inv;
    }

    // (11) fill vA/vM then reduce-scatter butterfly; one 64-lane store
    float vA[16], vM[16];
    const bool hi = (g4 >= 2);
    #pragma unroll
    for (int m = 0; m < 4; ++m){
      int src = 16*(m >> 1) + l15;
      float a0 = __shfl(wg0[(2*m) & 3],   src, 64);
      float b0 = __shfl(wg0[(2*m+1) & 3], src, 64);
      float a1 = __shfl(wg1[(2*m) & 3],   src, 64);
      float b1 = __shfl(wg1[(2*m+1) & 3], src, 64);
      float w0 = hi ? b0 : a0;
      float w1 = hi ? b1 : a1;
      #pragma unroll
      for (int r = 0; r < 4; ++r){
        vA[4*m+r] = acc[m][0][r]*w0 + acc[m][1][r]*w1;
        vM[4*m+r] = fmaxf(acc[m][0][r]*gm0, acc[m][1][r]*gm1);
      }
    }
    #pragma unroll
    for (int s = 0; s < 4; ++s){
      const int mm = 8 >> s;
      const bool up = (l15 & mm) != 0;
      #pragma unroll
      for (int k2 = 0; k2 < mm; ++k2){
        float sendA = up ? vA[k2] : vA[k2 + mm];
        float keepA = up ? vA[k2 + mm] : vA[k2];
        vA[k2] = keepA + __shfl_xor(sendA, mm, 64);
        float sendM = up ? vM[k2] : vM[k2 + mm];
        float keepM = up ? vM[k2 + mm] : vM[k2];
        vM[k2] = fmaxf(keepM, __shfl_xor(sendM, mm, 64));
      }
    }
    outb[4*it] = vA[0] + vM[0];
  }
}

extern "C" void kernel_launch(void* const* d_in, const int* in_sizes, int n_in,
                              void* d_out, int out_size, void* d_ws, size_t ws_size,
                              hipStream_t stream){
  (void)in_sizes; (void)n_in; (void)out_size; (void)ws_size;
  gsl_prep<<<dim3(1), dim3(512), 0, stream>>>(
    (const float*)d_in[7], (const float*)d_in[9], (const float*)d_in[10],
    (const float*)d_in[8], (float*)d_ws);
  gsl_fused<<<dim3(512), dim3(256), 0, stream>>>(
    (const float*)d_in[0],  (const float*)d_in[1],  (const float*)d_in[2],
    (const float*)d_in[3],  (const float*)d_in[4],  (const float*)d_in[5],
    (const float*)d_in[6],  (const float*)d_in[7],  (const float*)d_in[8],
    (const float*)d_in[11], (const float*)d_in[12], (const float*)d_in[13],
    (const float*)d_in[14], (const float*)d_in[15], (const float*)d_in[16],
    (const float*)d_in[17], (const float*)d_in[18], (const float*)d_in[19],
    (const float*)d_in[20], (const float*)d_in[21], (const float*)d_in[22],
    (const float*)d_in[23], (const float*)d_in[24], (const float*)d_in[25],
    (const float*)d_in[26], (const float*)d_in[27], (const float*)d_in[28],
    (const float*)d_in[29], (const float*)d_ws, (float*)d_out);
}